// Round 4
// baseline (452.060 us; speedup 1.0000x reference)
//
#include <hip/hip_runtime.h>

// ---------------------------------------------------------------------------
// GAT (3 layers) + attention pooling + regressor, full f32.
// N=20000 nodes, E=320000 edges (+N self loops), H=4 heads, C=64, B=16 graphs.
// ---------------------------------------------------------------------------

// ---------------- CSR-by-destination build ----------------
__global__ void edge_hist_k(const int* __restrict__ ei, int E, int n, int* __restrict__ deg) {
    int i = blockIdx.x * blockDim.x + threadIdx.x;
    if (i >= E + n) return;
    int dst = (i < E) ? ei[E + i] : (i - E);   // self-loop for i >= E
    atomicAdd(&deg[dst], 1);
}

__global__ __launch_bounds__(1024) void scan_excl_k(const int* __restrict__ deg, int* __restrict__ rowptr,
                                                    int* __restrict__ cursor, int n) {
    __shared__ int part[1024];
    int tid = threadIdx.x;
    int chunk = (n + 1023) / 1024;
    int lo = tid * chunk;
    int hi = lo + chunk;
    if (lo > n) lo = n;
    if (hi > n) hi = n;
    int s = 0;
    for (int i = lo; i < hi; ++i) s += deg[i];
    part[tid] = s;
    __syncthreads();
    for (int off = 1; off < 1024; off <<= 1) {
        int v = (tid >= off) ? part[tid - off] : 0;
        __syncthreads();
        part[tid] += v;
        __syncthreads();
    }
    int run = (tid == 0) ? 0 : part[tid - 1];
    for (int i = lo; i < hi; ++i) {
        rowptr[i] = run;
        cursor[i] = run;
        run += deg[i];
    }
    if (tid == 1023) rowptr[n] = run;
}

__global__ void edge_scatter_k(const int* __restrict__ ei, int E, int n,
                               int* __restrict__ cursor, int* __restrict__ srcs) {
    int i = blockIdx.x * blockDim.x + threadIdx.x;
    if (i >= E + n) return;
    int src, dst;
    if (i < E) { src = ei[i]; dst = ei[E + i]; }
    else       { src = i - E; dst = src; }
    int pos = atomicAdd(&cursor[dst], 1);
    srcs[pos] = src;
}

// ---------------- f32 GEMM, A streamed global->reg, B LDS double-buffered ---
// C[M,Nn] = A[M,K] @ B[K,Nn].  BN=64, BK=16, 256 threads.
// thread (tm,tn): tm=tid>>4 owns MR=BM/16 consecutive rows, tn=tid&15 owns 4 cols.
// A fragments: float4 along k, ping-pong prefetched; lanes with equal tm share
// the address (broadcast). Only B goes through LDS (1 b128 read per k).
#define KCHUNK(USE, PF, KBASE)                                                 \
    {                                                                          \
        int knext_ = (KBASE) + 4;                                              \
        if (knext_ < K) {                                                      \
            _Pragma("unroll") for (int i_ = 0; i_ < MR; ++i_)                  \
                PF[i_] = *reinterpret_cast<const float4*>(                     \
                    (const char*)A + aoff[i_] + (size_t)knext_ * 4);           \
        }                                                                      \
        _Pragma("unroll") for (int kk_ = 0; kk_ < 4; ++kk_) {                  \
            float4 bv_ = *reinterpret_cast<const float4*>(                     \
                &Bs[cur][((KBASE) & 15) + kk_][tn << 2]);                      \
            _Pragma("unroll") for (int i_ = 0; i_ < MR; ++i_) {                \
                float av_ = kk_ == 0 ? USE[i_].x                               \
                          : kk_ == 1 ? USE[i_].y                               \
                          : kk_ == 2 ? USE[i_].z : USE[i_].w;                  \
                acc[i_][0] = fmaf(av_, bv_.x, acc[i_][0]);                     \
                acc[i_][1] = fmaf(av_, bv_.y, acc[i_][1]);                     \
                acc[i_][2] = fmaf(av_, bv_.z, acc[i_][2]);                     \
                acc[i_][3] = fmaf(av_, bv_.w, acc[i_][3]);                     \
            }                                                                  \
        }                                                                      \
    }

template <int BM>
__global__ __launch_bounds__(256, 2) void gemm_as_k(const float* __restrict__ A,
                                                    const float* __restrict__ B,
                                                    float* __restrict__ C,
                                                    int M, int Nn, int K) {
    constexpr int MR = BM / 16;
    __shared__ float Bs[2][16][64];
    const int tid = threadIdx.x;
    const int tn = tid & 15;
    const int tm = tid >> 4;

    // bijective XCD-chunk swizzle (m204): consecutive logical wgs (which share
    // an A panel across the n-dimension) land on the same XCD's L2.
    int nwg = gridDim.x;
    int nt = Nn >> 6;
    int q = nwg >> 3, r = nwg & 7;
    int xcd = blockIdx.x & 7, pos = blockIdx.x >> 3;
    int wg = (xcd < r ? xcd * (q + 1) : r * (q + 1) + (xcd - r) * q) + pos;
    int m0 = (wg / nt) * BM;
    int n0 = (wg % nt) * 64;

    // per-thread A row byte-offsets (clamped so tail loads stay in bounds)
    int aoff[MR];
#pragma unroll
    for (int i = 0; i < MR; ++i) {
        int row = m0 + tm * MR + i;
        if (row > M - 1) row = M - 1;
        aoff[i] = row * K * 4;
    }
    float4 acur[MR], anxt[MR];
#pragma unroll
    for (int i = 0; i < MR; ++i)
        acur[i] = *reinterpret_cast<const float4*>((const char*)A + aoff[i]);

    // B staging: thread loads one float4 of the 16x64 tile
    const int bk = tid >> 4;          // 0..15
    const int bc = (tid & 15) << 2;   // 0..60
    float4 breg = *reinterpret_cast<const float4*>(&B[(size_t)bk * Nn + n0 + bc]);
    *reinterpret_cast<float4*>(&Bs[0][bk][bc]) = breg;
    __syncthreads();

    float acc[MR][4];
#pragma unroll
    for (int i = 0; i < MR; ++i)
#pragma unroll
        for (int j = 0; j < 4; ++j) acc[i][j] = 0.f;

    const int NT = K >> 4;
    for (int kt = 0; kt < NT; ++kt) {
        const int cur = kt & 1;
        if (kt + 1 < NT)
            breg = *reinterpret_cast<const float4*>(
                &B[(size_t)((kt + 1) * 16 + bk) * Nn + n0 + bc]);
        const int kb = kt << 4;
        KCHUNK(acur, anxt, kb + 0)
        KCHUNK(anxt, acur, kb + 4)
        KCHUNK(acur, anxt, kb + 8)
        KCHUNK(anxt, acur, kb + 12)
        __syncthreads();                      // all waves done reading Bs[cur]
        if (kt + 1 < NT)
            *reinterpret_cast<float4*>(&Bs[cur ^ 1][bk][bc]) = breg;
        __syncthreads();                      // Bs[cur^1] visible
    }

#pragma unroll
    for (int i = 0; i < MR; ++i) {
        int row = m0 + tm * MR + i;
        if (row < M) {
            float4 v = make_float4(acc[i][0], acc[i][1], acc[i][2], acc[i][3]);
            *reinterpret_cast<float4*>(&C[(size_t)row * Nn + n0 + (tn << 2)]) = v;
        }
    }
}

// ---------------- per-(node,head) attention scalars ----------------
__global__ void attn_scores4_k(const float* __restrict__ hin, const float* __restrict__ a_src,
                               const float* __restrict__ a_dst, float* __restrict__ esrc,
                               float* __restrict__ edst, int n) {
    int node = blockIdx.x * 4 + (threadIdx.x >> 6);
    int lane = threadIdx.x & 63;
    if (node >= n) return;
    float4 hv  = *reinterpret_cast<const float4*>(&hin[(size_t)node * 256 + lane * 4]);
    float4 asv = *reinterpret_cast<const float4*>(&a_src[lane * 4]);
    float4 adv = *reinterpret_cast<const float4*>(&a_dst[lane * 4]);
    float vs = hv.x * asv.x + hv.y * asv.y + hv.z * asv.z + hv.w * asv.w;
    float vd = hv.x * adv.x + hv.y * adv.y + hv.z * adv.z + hv.w * adv.w;
#pragma unroll
    for (int off = 8; off; off >>= 1) {
        vs += __shfl_xor(vs, off);
        vd += __shfl_xor(vd, off);
    }
    if ((lane & 15) == 0) {
        int h = lane >> 4;
        esrc[node * 4 + h] = vs;
        edst[node * 4 + h] = vd;
    }
}

__global__ void attn_scores1_k(const float* __restrict__ hin, const float* __restrict__ a_src,
                               const float* __restrict__ a_dst, float* __restrict__ esrc,
                               float* __restrict__ edst, int n) {
    int node = blockIdx.x * 4 + (threadIdx.x >> 6);
    int lane = threadIdx.x & 63;
    if (node >= n) return;
    float hv = hin[(size_t)node * 64 + lane];
    float vs = hv * a_src[lane];
    float vd = hv * a_dst[lane];
#pragma unroll
    for (int off = 32; off; off >>= 1) {
        vs += __shfl_xor(vs, off);
        vd += __shfl_xor(vd, off);
    }
    if (lane == 0) { esrc[node] = vs; edst[node] = vd; }
}

// ---------------- GAT aggregation, HEADS=4: one wave per dst node ----------
// lane l holds channels 4l..4l+3 (head = l>>4). srcs batched via lanes +
// __shfl broadcast; 2-deep prefetch of esrc + h rows.
__global__ __launch_bounds__(256) void gat_aggregate4_k(
        const float* __restrict__ hin, const float* __restrict__ esrc,
        const float* __restrict__ edst, const int* __restrict__ rowptr,
        const int* __restrict__ srcs, const float* __restrict__ bias,
        float* __restrict__ gout, int n) {
    int d = blockIdx.x * 4 + (threadIdx.x >> 6);
    int lane = threadIdx.x & 63;
    if (d >= n) return;
    int hh = lane >> 4;
    float ed = edst[d * 4 + hh];
    int lo = rowptr[d], hi = rowptr[d + 1];
    float4 acc = make_float4(0.f, 0.f, 0.f, 0.f);
    float den = 0.f;
    for (int base = lo; base < hi; base += 64) {
        int cnt = min(64, hi - base);
        int sv = (lane < cnt) ? srcs[base + lane] : 0;
        int s0 = __shfl(sv, 0);
        float es0 = esrc[s0 * 4 + hh];
        float4 h0 = *reinterpret_cast<const float4*>(&hin[(size_t)s0 * 256 + lane * 4]);
        float es1 = 0.f;
        float4 h1 = h0;
        if (cnt > 1) {
            int s1 = __shfl(sv, 1);
            es1 = esrc[s1 * 4 + hh];
            h1 = *reinterpret_cast<const float4*>(&hin[(size_t)s1 * 256 + lane * 4]);
        }
        for (int j = 0; j < cnt; ++j) {
            float es = es0;
            float4 hv = h0;
            es0 = es1; h0 = h1;
            if (j + 2 < cnt) {
                int s2 = __shfl(sv, j + 2);
                es1 = esrc[s2 * 4 + hh];
                h1 = *reinterpret_cast<const float4*>(&hin[(size_t)s2 * 256 + lane * 4]);
            }
            float e = es + ed;
            e = (e >= 0.f) ? e : 0.2f * e;       // leaky_relu(0.2)
            float w = __expf(e);
            den += w;
            acc.x = fmaf(w, hv.x, acc.x);
            acc.y = fmaf(w, hv.y, acc.y);
            acc.z = fmaf(w, hv.z, acc.z);
            acc.w = fmaf(w, hv.w, acc.w);
        }
    }
    float inv = 1.f / den;
    float4 bv = *reinterpret_cast<const float4*>(&bias[lane * 4]);
    float4 o;
    o.x = acc.x * inv + bv.x;
    o.y = acc.y * inv + bv.y;
    o.z = acc.z * inv + bv.z;
    o.w = acc.w * inv + bv.w;
    o.x = (o.x > 0.f) ? o.x : expm1f(o.x);       // ELU
    o.y = (o.y > 0.f) ? o.y : expm1f(o.y);
    o.z = (o.z > 0.f) ? o.z : expm1f(o.z);
    o.w = (o.w > 0.f) ? o.w : expm1f(o.w);
    *reinterpret_cast<float4*>(&gout[(size_t)d * 256 + lane * 4]) = o;
}

// ---------------- layer-3 aggregate (1 head) fused with node attn gate ------
__global__ __launch_bounds__(256) void gat_aggregate1_attn_k(
        const float* __restrict__ hin, const float* __restrict__ esrc,
        const float* __restrict__ edst, const int* __restrict__ rowptr,
        const int* __restrict__ srcs, const float* __restrict__ bias,
        const float* __restrict__ wp, const float* __restrict__ bp,
        float* __restrict__ gout, float* __restrict__ attn, int n) {
    int d = blockIdx.x * 4 + (threadIdx.x >> 6);
    int lane = threadIdx.x & 63;
    if (d >= n) return;
    float ed = edst[d];
    int lo = rowptr[d], hi = rowptr[d + 1];
    float den = 0.f, acc = 0.f;
    for (int base = lo; base < hi; base += 64) {
        int cnt = min(64, hi - base);
        int sv = (lane < cnt) ? srcs[base + lane] : 0;
        int s0 = __shfl(sv, 0);
        float es_nxt = esrc[s0];
        float h_nxt = hin[(size_t)s0 * 64 + lane];
        for (int j = 0; j < cnt; ++j) {
            float es = es_nxt;
            float hv = h_nxt;
            if (j + 1 < cnt) {
                int s1 = __shfl(sv, j + 1);
                es_nxt = esrc[s1];
                h_nxt = hin[(size_t)s1 * 64 + lane];
            }
            float e = es + ed;
            e = (e >= 0.f) ? e : 0.2f * e;
            float w = __expf(e);
            den += w;
            acc = fmaf(w, hv, acc);
        }
    }
    float o = acc / den + bias[lane];
    o = (o > 0.f) ? o : expm1f(o);               // ELU
    gout[(size_t)d * 64 + lane] = o;
    float v = o * wp[lane];
#pragma unroll
    for (int off = 32; off; off >>= 1) v += __shfl_xor(v, off);
    if (lane == 0) attn[d] = 1.f / (1.f + __expf(-(v + bp[0])));
}

// ---------------- parallel segmented pooling (batch is sorted) --------------
__global__ void pool_partial_k(const float* __restrict__ g3, const float* __restrict__ attn,
                               const int* __restrict__ batch, int n, float* __restrict__ sums) {
    int wid = blockIdx.x * (blockDim.x >> 6) + (threadIdx.x >> 6);
    int lane = threadIdx.x & 63;
    int nwaves = gridDim.x * (blockDim.x >> 6);
    int per = (n + nwaves - 1) / nwaves;
    int i0 = wid * per;
    int i1 = i0 + per;
    if (i1 > n) i1 = n;
    if (i0 >= i1) return;
    int cur = batch[i0];
    float acc = 0.f;
    for (int i = i0; i < i1; ++i) {
        int b = batch[i];
        if (b != cur) {
            atomicAdd(&sums[cur * 64 + lane], acc);
            acc = 0.f;
            cur = b;
        }
        acc += g3[(size_t)i * 64 + lane] * attn[i];
    }
    atomicAdd(&sums[cur * 64 + lane], acc);
}

// ---------------- final regressor: one block, wave per graph ----------------
__global__ void regress_k(const float* __restrict__ sums, const int* __restrict__ batch, int n,
                          const float* __restrict__ wr, const float* __restrict__ br,
                          float* __restrict__ out, int B) {
    int b = threadIdx.x >> 6;
    int lane = threadIdx.x & 63;
    if (b >= B) return;
    int lo = 0, hi = n;
    while (lo < hi) { int mid = (lo + hi) >> 1; if (batch[mid] < b) lo = mid + 1; else hi = mid; }
    int seg_lo = lo;
    lo = 0; hi = n;
    while (lo < hi) { int mid = (lo + hi) >> 1; if (batch[mid] < b + 1) lo = mid + 1; else hi = mid; }
    float cnt = (float)(lo - seg_lo);
    if (cnt < 1.f) cnt = 1.f;
    float v = (sums[b * 64 + lane] / cnt) * wr[lane];
#pragma unroll
    for (int off = 32; off; off >>= 1) v += __shfl_xor(v, off);
    if (lane == 0) out[b] = v + br[0];
}

// ---------------------------------------------------------------------------
extern "C" void kernel_launch(void* const* d_in, const int* in_sizes, int n_in,
                              void* d_out, int out_size, void* d_ws, size_t ws_size,
                              hipStream_t stream) {
    const float* x   = (const float*)d_in[0];
    const int*   ei  = (const int*)d_in[1];
    const int*   bat = (const int*)d_in[2];
    const float* W1  = (const float*)d_in[3];
    const float* as1 = (const float*)d_in[4];
    const float* ad1 = (const float*)d_in[5];
    const float* b1  = (const float*)d_in[6];
    const float* W2  = (const float*)d_in[7];
    const float* as2 = (const float*)d_in[8];
    const float* ad2 = (const float*)d_in[9];
    const float* b2  = (const float*)d_in[10];
    const float* W3  = (const float*)d_in[11];
    const float* as3 = (const float*)d_in[12];
    const float* ad3 = (const float*)d_in[13];
    const float* b3  = (const float*)d_in[14];
    const float* wp  = (const float*)d_in[15];
    const float* bp  = (const float*)d_in[16];
    const float* wr  = (const float*)d_in[17];
    const float* br  = (const float*)d_in[18];
    float* out = (float*)d_out;

    const int N    = in_sizes[2];          // 20000
    const int E    = in_sizes[1] / 2;      // 320000
    const int DIN  = in_sizes[0] / N;      // 128
    const int Etot = E + N;
    const int Bc   = out_size;             // 16

    char* ws = (char*)d_ws;
    size_t off = 0;
    auto alloc = [&](size_t bytes) {
        void* p = ws + off;
        off = (off + bytes + 255) & ~(size_t)255;
        return p;
    };
    int*   deg    = (int*)alloc((size_t)N * 4);
    int*   rowptr = (int*)alloc((size_t)(N + 1) * 4);
    int*   cursor = (int*)alloc((size_t)N * 4);
    int*   srcs   = (int*)alloc((size_t)Etot * 4);
    float* bufA   = (float*)alloc((size_t)N * 256 * 4);   // h1, then h2
    float* bufB   = (float*)alloc((size_t)N * 256 * 4);   // g1, then g2
    float* h3     = (float*)alloc((size_t)N * 64 * 4);
    float* g3     = (float*)alloc((size_t)N * 64 * 4);
    float* esrc   = (float*)alloc((size_t)N * 4 * 4);
    float* edst   = (float*)alloc((size_t)N * 4 * 4);
    float* attn   = (float*)alloc((size_t)N * 4);
    float* sums   = (float*)alloc((size_t)Bc * 64 * 4);
    (void)ws_size;

    // CSR build (shared by all layers)
    hipMemsetAsync(deg, 0, (size_t)N * 4, stream);
    int eb = (Etot + 255) / 256;
    edge_hist_k<<<eb, 256, 0, stream>>>(ei, E, N, deg);
    scan_excl_k<<<1, 1024, 0, stream>>>(deg, rowptr, cursor, N);
    edge_scatter_k<<<eb, 256, 0, stream>>>(ei, E, N, cursor, srcs);

    const int mt128 = (N + 127) / 128;     // 157
    const int mt64  = (N + 63) / 64;       // 313
    int nb4 = (N + 3) / 4;

    // Layer 1: DIN -> (4,64) concat
    gemm_as_k<128><<<mt128 * 4, 256, 0, stream>>>(x, W1, bufA, N, 256, DIN);
    attn_scores4_k<<<nb4, 256, 0, stream>>>(bufA, as1, ad1, esrc, edst, N);
    gat_aggregate4_k<<<nb4, 256, 0, stream>>>(bufA, esrc, edst, rowptr, srcs, b1, bufB, N);

    // Layer 2: 256 -> (4,64) concat
    gemm_as_k<128><<<mt128 * 4, 256, 0, stream>>>(bufB, W2, bufA, N, 256, 256);
    attn_scores4_k<<<nb4, 256, 0, stream>>>(bufA, as2, ad2, esrc, edst, N);
    gat_aggregate4_k<<<nb4, 256, 0, stream>>>(bufA, esrc, edst, rowptr, srcs, b2, bufB, N);

    // Layer 3: 256 -> (1,64) mean + fused node-attention gate
    gemm_as_k<64><<<mt64, 256, 0, stream>>>(bufB, W3, h3, N, 64, 256);
    attn_scores1_k<<<nb4, 256, 0, stream>>>(h3, as3, ad3, esrc, edst, N);
    gat_aggregate1_attn_k<<<nb4, 256, 0, stream>>>(h3, esrc, edst, rowptr, srcs, b3, wp, bp, g3, attn, N);

    // Attention pool + regressor (parallel)
    hipMemsetAsync(sums, 0, (size_t)Bc * 64 * 4, stream);
    pool_partial_k<<<256, 256, 0, stream>>>(g3, attn, bat, N, sums);
    regress_k<<<1, 1024, 0, stream>>>(sums, bat, N, wr, br, out, Bc);
}

// Round 5
// 343.805 us; speedup vs baseline: 1.3149x; 1.3149x over previous
//
#include <hip/hip_runtime.h>

// ---------------------------------------------------------------------------
// GAT (3 layers) + attention pooling + regressor.
// GEMMs: split-bf16 MFMA (a_hi+a_lo decomposition, 3 products, f32 accum).
// N=20000 nodes, E=320000 edges (+N self loops), H=4 heads, C=64, B=16 graphs.
// ---------------------------------------------------------------------------

typedef unsigned short u16;
typedef __attribute__((ext_vector_type(8))) short bf16x8;
typedef __attribute__((ext_vector_type(4))) float f32x4;

__device__ __forceinline__ u16 bf16rn(float x) {
    unsigned u = __float_as_uint(x);
    u += 0x7FFFu + ((u >> 16) & 1u);
    return (u16)(u >> 16);
}
__device__ __forceinline__ float bf16f(u16 h) {
    return __uint_as_float(((unsigned)h) << 16);
}

// ---------------- CSR-by-destination build ----------------
__global__ void edge_hist_k(const int* __restrict__ ei, int E, int n, int* __restrict__ deg) {
    int i = blockIdx.x * blockDim.x + threadIdx.x;
    if (i >= E + n) return;
    int dst = (i < E) ? ei[E + i] : (i - E);   // self-loop for i >= E
    atomicAdd(&deg[dst], 1);
}

__global__ __launch_bounds__(1024) void scan_excl_k(const int* __restrict__ deg, int* __restrict__ rowptr,
                                                    int* __restrict__ cursor, int n) {
    __shared__ int part[1024];
    int tid = threadIdx.x;
    int chunk = (n + 1023) / 1024;
    int lo = tid * chunk;
    int hi = lo + chunk;
    if (lo > n) lo = n;
    if (hi > n) hi = n;
    int s = 0;
    for (int i = lo; i < hi; ++i) s += deg[i];
    part[tid] = s;
    __syncthreads();
    for (int off = 1; off < 1024; off <<= 1) {
        int v = (tid >= off) ? part[tid - off] : 0;
        __syncthreads();
        part[tid] += v;
        __syncthreads();
    }
    int run = (tid == 0) ? 0 : part[tid - 1];
    for (int i = lo; i < hi; ++i) {
        rowptr[i] = run;
        cursor[i] = run;
        run += deg[i];
    }
    if (tid == 1023) rowptr[n] = run;
}

__global__ void edge_scatter_k(const int* __restrict__ ei, int E, int n,
                               int* __restrict__ cursor, int* __restrict__ srcs) {
    int i = blockIdx.x * blockDim.x + threadIdx.x;
    if (i >= E + n) return;
    int src, dst;
    if (i < E) { src = ei[i]; dst = ei[E + i]; }
    else       { src = i - E; dst = src; }
    int pos = atomicAdd(&cursor[dst], 1);
    srcs[pos] = src;
}

// ---------------- bf16 split conversions ----------------
// elementwise: in[M*K] f32 -> hi, lo bf16 (same row-major layout)
__global__ void split_bf16_k(const float* __restrict__ in, u16* __restrict__ hi,
                             u16* __restrict__ lo, int n4) {
    int i = blockIdx.x * 256 + threadIdx.x;
    if (i >= n4) return;
    float4 v = reinterpret_cast<const float4*>(in)[i];
    u16 hx = bf16rn(v.x), hy = bf16rn(v.y), hz = bf16rn(v.z), hw = bf16rn(v.w);
    ushort4 H = make_ushort4(hx, hy, hz, hw);
    ushort4 L = make_ushort4(bf16rn(v.x - bf16f(hx)), bf16rn(v.y - bf16f(hy)),
                             bf16rn(v.z - bf16f(hz)), bf16rn(v.w - bf16f(hw)));
    reinterpret_cast<ushort4*>(hi)[i] = H;
    reinterpret_cast<ushort4*>(lo)[i] = L;
}

// W[K][Nn] row-major -> transposed split Wt[Nn][K] (hi, lo)
__global__ void splitT_bf16_k(const float* __restrict__ W, u16* __restrict__ thi,
                              u16* __restrict__ tlo, int K, int Nn) {
    int idx = blockIdx.x * 256 + threadIdx.x;
    if (idx >= K * Nn) return;
    int k = idx / Nn, nn = idx - k * Nn;
    float v = W[idx];
    u16 h = bf16rn(v);
    u16 l = bf16rn(v - bf16f(h));
    thi[(size_t)nn * K + k] = h;
    tlo[(size_t)nn * K + k] = l;
}

// ---------------- split-bf16 MFMA GEMM ----------------
// C[M,Nn] = (Ahi+Alo)[M,K] @ (Bhi+Blo)[K,Nn]  (lo*lo term dropped, ~2^-18 rel)
// Bt* are transposed [Nn][K]. Block: 64x64 tile, 256 threads = 4 waves,
// wave w owns cols w*16..w*16+15, all 64 rows (4 m-fragments).
// mfma_f32_16x16x32_bf16: A lane l holds row (l&15), k = (l>>4)*8..+8 (contig);
// C/D: col = lane&15, row = (lane>>4)*4 + reg.
__global__ __launch_bounds__(256) void gemm_mfma_k(
        const u16* __restrict__ Ahi, const u16* __restrict__ Alo,
        const u16* __restrict__ Bthi, const u16* __restrict__ Btlo,
        float* __restrict__ C, int M, int Nn, int K) {
    const int nt = Nn >> 6;
    // bijective XCD-chunk swizzle: consecutive logical wgs (sharing an A panel)
    // land on the same XCD's L2.
    int nwg = gridDim.x;
    int q = nwg >> 3, r = nwg & 7;
    int xcd = blockIdx.x & 7, pos = blockIdx.x >> 3;
    int wg = (xcd < r ? xcd * (q + 1) : r * (q + 1) + (xcd - r) * q) + pos;
    const int m0 = (wg / nt) * 64;
    const int n0 = (wg % nt) * 64;
    const int wv = threadIdx.x >> 6;
    const int lane = threadIdx.x & 63;
    const int rrow = lane & 15;
    const int kg = lane >> 4;          // 0..3 -> k offset kg*8

    const u16* pah[4];
    const u16* pal[4];
#pragma unroll
    for (int mf = 0; mf < 4; ++mf) {
        int row = m0 + mf * 16 + rrow;
        if (row > M - 1) row = M - 1;          // clamp; guarded at store
        pah[mf] = Ahi + (size_t)row * K + kg * 8;
        pal[mf] = Alo + (size_t)row * K + kg * 8;
    }
    const int bcol = n0 + wv * 16 + rrow;
    const u16* pbh = Bthi + (size_t)bcol * K + kg * 8;
    const u16* pbl = Btlo + (size_t)bcol * K + kg * 8;

    f32x4 acc[4];
#pragma unroll
    for (int mf = 0; mf < 4; ++mf) acc[mf] = (f32x4){0.f, 0.f, 0.f, 0.f};

    bf16x8 bh0, bl0, ah0[4], al0[4];
    bf16x8 bh1, bl1, ah1[4], al1[4];

#define LOADF(KC, BH, BL, AH, AL)                                           \
    {                                                                       \
        BH = *reinterpret_cast<const bf16x8*>(pbh + (KC));                  \
        BL = *reinterpret_cast<const bf16x8*>(pbl + (KC));                  \
        _Pragma("unroll") for (int mf_ = 0; mf_ < 4; ++mf_) {               \
            AH[mf_] = *reinterpret_cast<const bf16x8*>(pah[mf_] + (KC));    \
            AL[mf_] = *reinterpret_cast<const bf16x8*>(pal[mf_] + (KC));    \
        }                                                                   \
    }
#define MFMAS(BH, BL, AH, AL)                                               \
    {                                                                       \
        _Pragma("unroll") for (int mf_ = 0; mf_ < 4; ++mf_) {               \
            acc[mf_] = __builtin_amdgcn_mfma_f32_16x16x32_bf16(AH[mf_], BH, acc[mf_], 0, 0, 0); \
            acc[mf_] = __builtin_amdgcn_mfma_f32_16x16x32_bf16(AH[mf_], BL, acc[mf_], 0, 0, 0); \
            acc[mf_] = __builtin_amdgcn_mfma_f32_16x16x32_bf16(AL[mf_], BH, acc[mf_], 0, 0, 0); \
        }                                                                   \
    }

    LOADF(0, bh0, bl0, ah0, al0)
    for (int kc = 0; kc < K; kc += 64) {       // K is a multiple of 64
        if (kc + 32 < K) LOADF(kc + 32, bh1, bl1, ah1, al1)
        MFMAS(bh0, bl0, ah0, al0)
        if (kc + 64 < K) LOADF(kc + 64, bh0, bl0, ah0, al0)
        if (kc + 32 < K) MFMAS(bh1, bl1, ah1, al1)
    }
#undef LOADF
#undef MFMAS

    const int ccol = n0 + wv * 16 + (lane & 15);
#pragma unroll
    for (int mf = 0; mf < 4; ++mf) {
#pragma unroll
        for (int rg = 0; rg < 4; ++rg) {
            int row = m0 + mf * 16 + kg * 4 + rg;
            if (row < M) C[(size_t)row * Nn + ccol] = acc[mf][rg];
        }
    }
}

// ---------------- per-(node,head) attention scalars ----------------
__global__ void attn_scores4_k(const float* __restrict__ hin, const float* __restrict__ a_src,
                               const float* __restrict__ a_dst, float* __restrict__ esrc,
                               float* __restrict__ edst, int n) {
    int node = blockIdx.x * 4 + (threadIdx.x >> 6);
    int lane = threadIdx.x & 63;
    if (node >= n) return;
    float4 hv  = *reinterpret_cast<const float4*>(&hin[(size_t)node * 256 + lane * 4]);
    float4 asv = *reinterpret_cast<const float4*>(&a_src[lane * 4]);
    float4 adv = *reinterpret_cast<const float4*>(&a_dst[lane * 4]);
    float vs = hv.x * asv.x + hv.y * asv.y + hv.z * asv.z + hv.w * asv.w;
    float vd = hv.x * adv.x + hv.y * adv.y + hv.z * adv.z + hv.w * adv.w;
#pragma unroll
    for (int off = 8; off; off >>= 1) {
        vs += __shfl_xor(vs, off);
        vd += __shfl_xor(vd, off);
    }
    if ((lane & 15) == 0) {
        int h = lane >> 4;
        esrc[node * 4 + h] = vs;
        edst[node * 4 + h] = vd;
    }
}

__global__ void attn_scores1_k(const float* __restrict__ hin, const float* __restrict__ a_src,
                               const float* __restrict__ a_dst, float* __restrict__ esrc,
                               float* __restrict__ edst, int n) {
    int node = blockIdx.x * 4 + (threadIdx.x >> 6);
    int lane = threadIdx.x & 63;
    if (node >= n) return;
    float hv = hin[(size_t)node * 64 + lane];
    float vs = hv * a_src[lane];
    float vd = hv * a_dst[lane];
#pragma unroll
    for (int off = 32; off; off >>= 1) {
        vs += __shfl_xor(vs, off);
        vd += __shfl_xor(vd, off);
    }
    if (lane == 0) { esrc[node] = vs; edst[node] = vd; }
}

// ---------------- GAT aggregation, HEADS=4: one wave per dst node ----------
// Fused epilogue: output written as split bf16 (hi/lo) for the next MFMA GEMM.
__global__ __launch_bounds__(256) void gat_aggregate4_k(
        const float* __restrict__ hin, const float* __restrict__ esrc,
        const float* __restrict__ edst, const int* __restrict__ rowptr,
        const int* __restrict__ srcs, const float* __restrict__ bias,
        u16* __restrict__ ghi, u16* __restrict__ glo, int n) {
    int d = blockIdx.x * 4 + (threadIdx.x >> 6);
    int lane = threadIdx.x & 63;
    if (d >= n) return;
    int hh = lane >> 4;
    float ed = edst[d * 4 + hh];
    int lo = rowptr[d], hi = rowptr[d + 1];
    float4 acc = make_float4(0.f, 0.f, 0.f, 0.f);
    float den = 0.f;
    for (int base = lo; base < hi; base += 64) {
        int cnt = min(64, hi - base);
        int sv = (lane < cnt) ? srcs[base + lane] : 0;
        int s0 = __shfl(sv, 0);
        float es0 = esrc[s0 * 4 + hh];
        float4 h0 = *reinterpret_cast<const float4*>(&hin[(size_t)s0 * 256 + lane * 4]);
        float es1 = 0.f;
        float4 h1 = h0;
        if (cnt > 1) {
            int s1 = __shfl(sv, 1);
            es1 = esrc[s1 * 4 + hh];
            h1 = *reinterpret_cast<const float4*>(&hin[(size_t)s1 * 256 + lane * 4]);
        }
        for (int j = 0; j < cnt; ++j) {
            float es = es0;
            float4 hv = h0;
            es0 = es1; h0 = h1;
            if (j + 2 < cnt) {
                int s2 = __shfl(sv, j + 2);
                es1 = esrc[s2 * 4 + hh];
                h1 = *reinterpret_cast<const float4*>(&hin[(size_t)s2 * 256 + lane * 4]);
            }
            float e = es + ed;
            e = (e >= 0.f) ? e : 0.2f * e;       // leaky_relu(0.2)
            float w = __expf(e);
            den += w;
            acc.x = fmaf(w, hv.x, acc.x);
            acc.y = fmaf(w, hv.y, acc.y);
            acc.z = fmaf(w, hv.z, acc.z);
            acc.w = fmaf(w, hv.w, acc.w);
        }
    }
    float inv = 1.f / den;
    float4 bv = *reinterpret_cast<const float4*>(&bias[lane * 4]);
    float4 o;
    o.x = acc.x * inv + bv.x;
    o.y = acc.y * inv + bv.y;
    o.z = acc.z * inv + bv.z;
    o.w = acc.w * inv + bv.w;
    o.x = (o.x > 0.f) ? o.x : expm1f(o.x);       // ELU
    o.y = (o.y > 0.f) ? o.y : expm1f(o.y);
    o.z = (o.z > 0.f) ? o.z : expm1f(o.z);
    o.w = (o.w > 0.f) ? o.w : expm1f(o.w);
    u16 hx = bf16rn(o.x), hy = bf16rn(o.y), hz = bf16rn(o.z), hw = bf16rn(o.w);
    ushort4 H = make_ushort4(hx, hy, hz, hw);
    ushort4 L = make_ushort4(bf16rn(o.x - bf16f(hx)), bf16rn(o.y - bf16f(hy)),
                             bf16rn(o.z - bf16f(hz)), bf16rn(o.w - bf16f(hw)));
    *reinterpret_cast<ushort4*>(&ghi[(size_t)d * 256 + lane * 4]) = H;
    *reinterpret_cast<ushort4*>(&glo[(size_t)d * 256 + lane * 4]) = L;
}

// ---------------- layer-3 aggregate (1 head) fused with node attn gate ------
__global__ __launch_bounds__(256) void gat_aggregate1_attn_k(
        const float* __restrict__ hin, const float* __restrict__ esrc,
        const float* __restrict__ edst, const int* __restrict__ rowptr,
        const int* __restrict__ srcs, const float* __restrict__ bias,
        const float* __restrict__ wp, const float* __restrict__ bp,
        float* __restrict__ gout, float* __restrict__ attn, int n) {
    int d = blockIdx.x * 4 + (threadIdx.x >> 6);
    int lane = threadIdx.x & 63;
    if (d >= n) return;
    float ed = edst[d];
    int lo = rowptr[d], hi = rowptr[d + 1];
    float den = 0.f, acc = 0.f;
    for (int base = lo; base < hi; base += 64) {
        int cnt = min(64, hi - base);
        int sv = (lane < cnt) ? srcs[base + lane] : 0;
        int s0 = __shfl(sv, 0);
        float es_nxt = esrc[s0];
        float h_nxt = hin[(size_t)s0 * 64 + lane];
        for (int j = 0; j < cnt; ++j) {
            float es = es_nxt;
            float hv = h_nxt;
            if (j + 1 < cnt) {
                int s1 = __shfl(sv, j + 1);
                es_nxt = esrc[s1];
                h_nxt = hin[(size_t)s1 * 64 + lane];
            }
            float e = es + ed;
            e = (e >= 0.f) ? e : 0.2f * e;
            float w = __expf(e);
            den += w;
            acc = fmaf(w, hv, acc);
        }
    }
    float o = acc / den + bias[lane];
    o = (o > 0.f) ? o : expm1f(o);               // ELU
    gout[(size_t)d * 64 + lane] = o;
    float v = o * wp[lane];
#pragma unroll
    for (int off = 32; off; off >>= 1) v += __shfl_xor(v, off);
    if (lane == 0) attn[d] = 1.f / (1.f + __expf(-(v + bp[0])));
}

// ---------------- parallel segmented pooling (batch is sorted) --------------
__global__ void pool_partial_k(const float* __restrict__ g3, const float* __restrict__ attn,
                               const int* __restrict__ batch, int n, float* __restrict__ sums) {
    int wid = blockIdx.x * (blockDim.x >> 6) + (threadIdx.x >> 6);
    int lane = threadIdx.x & 63;
    int nwaves = gridDim.x * (blockDim.x >> 6);
    int per = (n + nwaves - 1) / nwaves;
    int i0 = wid * per;
    int i1 = i0 + per;
    if (i1 > n) i1 = n;
    if (i0 >= i1) return;
    int cur = batch[i0];
    float acc = 0.f;
    for (int i = i0; i < i1; ++i) {
        int b = batch[i];
        if (b != cur) {
            atomicAdd(&sums[cur * 64 + lane], acc);
            acc = 0.f;
            cur = b;
        }
        acc += g3[(size_t)i * 64 + lane] * attn[i];
    }
    atomicAdd(&sums[cur * 64 + lane], acc);
}

// ---------------- final regressor: one block, wave per graph ----------------
__global__ void regress_k(const float* __restrict__ sums, const int* __restrict__ batch, int n,
                          const float* __restrict__ wr, const float* __restrict__ br,
                          float* __restrict__ out, int B) {
    int b = threadIdx.x >> 6;
    int lane = threadIdx.x & 63;
    if (b >= B) return;
    int lo = 0, hi = n;
    while (lo < hi) { int mid = (lo + hi) >> 1; if (batch[mid] < b) lo = mid + 1; else hi = mid; }
    int seg_lo = lo;
    lo = 0; hi = n;
    while (lo < hi) { int mid = (lo + hi) >> 1; if (batch[mid] < b + 1) lo = mid + 1; else hi = mid; }
    float cnt = (float)(lo - seg_lo);
    if (cnt < 1.f) cnt = 1.f;
    float v = (sums[b * 64 + lane] / cnt) * wr[lane];
#pragma unroll
    for (int off = 32; off; off >>= 1) v += __shfl_xor(v, off);
    if (lane == 0) out[b] = v + br[0];
}

// ---------------------------------------------------------------------------
extern "C" void kernel_launch(void* const* d_in, const int* in_sizes, int n_in,
                              void* d_out, int out_size, void* d_ws, size_t ws_size,
                              hipStream_t stream) {
    const float* x   = (const float*)d_in[0];
    const int*   ei  = (const int*)d_in[1];
    const int*   bat = (const int*)d_in[2];
    const float* W1  = (const float*)d_in[3];
    const float* as1 = (const float*)d_in[4];
    const float* ad1 = (const float*)d_in[5];
    const float* b1  = (const float*)d_in[6];
    const float* W2  = (const float*)d_in[7];
    const float* as2 = (const float*)d_in[8];
    const float* ad2 = (const float*)d_in[9];
    const float* b2  = (const float*)d_in[10];
    const float* W3  = (const float*)d_in[11];
    const float* as3 = (const float*)d_in[12];
    const float* ad3 = (const float*)d_in[13];
    const float* b3  = (const float*)d_in[14];
    const float* wp  = (const float*)d_in[15];
    const float* bp  = (const float*)d_in[16];
    const float* wr  = (const float*)d_in[17];
    const float* br  = (const float*)d_in[18];
    float* out = (float*)d_out;

    const int N    = in_sizes[2];          // 20000
    const int E    = in_sizes[1] / 2;      // 320000
    const int DIN  = in_sizes[0] / N;      // 128
    const int Etot = E + N;
    const int Bc   = out_size;             // 16

    char* ws = (char*)d_ws;
    size_t off = 0;
    auto alloc = [&](size_t bytes) {
        void* p = ws + off;
        off = (off + bytes + 255) & ~(size_t)255;
        return p;
    };
    int*   deg    = (int*)alloc((size_t)N * 4);
    int*   rowptr = (int*)alloc((size_t)(N + 1) * 4);
    int*   cursor = (int*)alloc((size_t)N * 4);
    int*   srcs   = (int*)alloc((size_t)Etot * 4);
    float* bufA   = (float*)alloc((size_t)N * 256 * 4);     // GEMM out h (f32)
    u16*   Ahi    = (u16*)alloc((size_t)N * 256 * 2);       // x/g split hi
    u16*   Alo    = (u16*)alloc((size_t)N * 256 * 2);       // x/g split lo
    float* h3     = (float*)alloc((size_t)N * 64 * 4);
    float* g3     = (float*)alloc((size_t)N * 64 * 4);
    float* esrc   = (float*)alloc((size_t)N * 4 * 4);
    float* edst   = (float*)alloc((size_t)N * 4 * 4);
    float* attn   = (float*)alloc((size_t)N * 4);
    float* sums   = (float*)alloc((size_t)Bc * 64 * 4);
    u16*   w1hi   = (u16*)alloc((size_t)256 * DIN * 2);
    u16*   w1lo   = (u16*)alloc((size_t)256 * DIN * 2);
    u16*   w2hi   = (u16*)alloc((size_t)256 * 256 * 2);
    u16*   w2lo   = (u16*)alloc((size_t)256 * 256 * 2);
    u16*   w3hi   = (u16*)alloc((size_t)64 * 256 * 2);
    u16*   w3lo   = (u16*)alloc((size_t)64 * 256 * 2);
    (void)ws_size;

    // CSR build (shared by all layers)
    hipMemsetAsync(deg, 0, (size_t)N * 4, stream);
    int eb = (Etot + 255) / 256;
    edge_hist_k<<<eb, 256, 0, stream>>>(ei, E, N, deg);
    scan_excl_k<<<1, 1024, 0, stream>>>(deg, rowptr, cursor, N);
    edge_scatter_k<<<eb, 256, 0, stream>>>(ei, E, N, cursor, srcs);

    // weight splits (transposed) + x split
    splitT_bf16_k<<<(DIN * 256 + 255) / 256, 256, 0, stream>>>(W1, w1hi, w1lo, DIN, 256);
    splitT_bf16_k<<<(256 * 256 + 255) / 256, 256, 0, stream>>>(W2, w2hi, w2lo, 256, 256);
    splitT_bf16_k<<<(256 * 64 + 255) / 256, 256, 0, stream>>>(W3, w3hi, w3lo, 256, 64);
    split_bf16_k<<<(N * DIN / 4 + 255) / 256, 256, 0, stream>>>(x, Ahi, Alo, N * DIN / 4);

    const int mt = (N + 63) / 64;          // 313
    int nb4 = (N + 3) / 4;

    // Layer 1: DIN -> (4,64) concat
    gemm_mfma_k<<<mt * 4, 256, 0, stream>>>(Ahi, Alo, w1hi, w1lo, bufA, N, 256, DIN);
    attn_scores4_k<<<nb4, 256, 0, stream>>>(bufA, as1, ad1, esrc, edst, N);
    gat_aggregate4_k<<<nb4, 256, 0, stream>>>(bufA, esrc, edst, rowptr, srcs, b1, Ahi, Alo, N);

    // Layer 2: 256 -> (4,64) concat
    gemm_mfma_k<<<mt * 4, 256, 0, stream>>>(Ahi, Alo, w2hi, w2lo, bufA, N, 256, 256);
    attn_scores4_k<<<nb4, 256, 0, stream>>>(bufA, as2, ad2, esrc, edst, N);
    gat_aggregate4_k<<<nb4, 256, 0, stream>>>(bufA, esrc, edst, rowptr, srcs, b2, Ahi, Alo, N);

    // Layer 3: 256 -> (1,64) mean + fused node-attention gate
    gemm_mfma_k<<<mt, 256, 0, stream>>>(Ahi, Alo, w3hi, w3lo, h3, N, 64, 256);
    attn_scores1_k<<<nb4, 256, 0, stream>>>(h3, as3, ad3, esrc, edst, N);
    gat_aggregate1_attn_k<<<nb4, 256, 0, stream>>>(h3, esrc, edst, rowptr, srcs, b3, wp, bp, g3, attn, N);

    // Attention pool + regressor (parallel)
    hipMemsetAsync(sums, 0, (size_t)Bc * 64 * 4, stream);
    pool_partial_k<<<256, 256, 0, stream>>>(g3, attn, bat, N, sums);
    regress_k<<<1, 1024, 0, stream>>>(sums, bat, N, wr, br, out, Bc);
}

// Round 6
// 298.209 us; speedup vs baseline: 1.5159x; 1.1529x over previous
//
#include <hip/hip_runtime.h>

// ---------------------------------------------------------------------------
// GAT (3 layers) + attention pooling + regressor.
// GEMMs: split-bf16 MFMA (a_hi+a_lo, 3 products, f32 accum), A staged in LDS
// via global_load_lds (k-major granules), B reg-prefetched from L2.
// N=20000 nodes, E=320000 edges (+N self loops), H=4 heads, C=64, B=16 graphs.
// ---------------------------------------------------------------------------

typedef unsigned short u16;
typedef __attribute__((ext_vector_type(8))) short bf16x8;
typedef __attribute__((ext_vector_type(4))) float f32x4;

__device__ __forceinline__ u16 bf16rn(float x) {
    unsigned u = __float_as_uint(x);
    u += 0x7FFFu + ((u >> 16) & 1u);
    return (u16)(u >> 16);
}
__device__ __forceinline__ float bf16f(u16 h) {
    return __uint_as_float(((unsigned)h) << 16);
}

__device__ __forceinline__ void gload16(const u16* g, u16* l) {
    __builtin_amdgcn_global_load_lds(
        (const __attribute__((address_space(1))) unsigned int*)g,
        (__attribute__((address_space(3))) unsigned int*)l, 16, 0, 0);
}

// ---------------- CSR-by-destination build ----------------
__global__ void edge_hist_k(const int* __restrict__ ei, int E, int n, int* __restrict__ deg) {
    int i = blockIdx.x * blockDim.x + threadIdx.x;
    if (i >= E + n) return;
    int dst = (i < E) ? ei[E + i] : (i - E);   // self-loop for i >= E
    atomicAdd(&deg[dst], 1);
}

__global__ __launch_bounds__(1024) void scan_excl_k(const int* __restrict__ deg, int* __restrict__ rowptr,
                                                    int* __restrict__ cursor, int n) {
    __shared__ int part[1024];
    int tid = threadIdx.x;
    int chunk = (n + 1023) / 1024;
    int lo = tid * chunk;
    int hi = lo + chunk;
    if (lo > n) lo = n;
    if (hi > n) hi = n;
    int s = 0;
    for (int i = lo; i < hi; ++i) s += deg[i];
    part[tid] = s;
    __syncthreads();
    for (int off = 1; off < 1024; off <<= 1) {
        int v = (tid >= off) ? part[tid - off] : 0;
        __syncthreads();
        part[tid] += v;
        __syncthreads();
    }
    int run = (tid == 0) ? 0 : part[tid - 1];
    for (int i = lo; i < hi; ++i) {
        rowptr[i] = run;
        cursor[i] = run;
        run += deg[i];
    }
    if (tid == 1023) rowptr[n] = run;
}

__global__ void edge_scatter_k(const int* __restrict__ ei, int E, int n,
                               int* __restrict__ cursor, int* __restrict__ srcs) {
    int i = blockIdx.x * blockDim.x + threadIdx.x;
    if (i >= E + n) return;
    int src, dst;
    if (i < E) { src = ei[i]; dst = ei[E + i]; }
    else       { src = i - E; dst = src; }
    int pos = atomicAdd(&cursor[dst], 1);
    srcs[pos] = src;
}

// ---------------- bf16 split conversions ----------------
__global__ void split_bf16_k(const float* __restrict__ in, u16* __restrict__ hi,
                             u16* __restrict__ lo, int n4) {
    int i = blockIdx.x * 256 + threadIdx.x;
    if (i >= n4) return;
    float4 v = reinterpret_cast<const float4*>(in)[i];
    u16 hx = bf16rn(v.x), hy = bf16rn(v.y), hz = bf16rn(v.z), hw = bf16rn(v.w);
    ushort4 H = make_ushort4(hx, hy, hz, hw);
    ushort4 L = make_ushort4(bf16rn(v.x - bf16f(hx)), bf16rn(v.y - bf16f(hy)),
                             bf16rn(v.z - bf16f(hz)), bf16rn(v.w - bf16f(hw)));
    reinterpret_cast<ushort4*>(hi)[i] = H;
    reinterpret_cast<ushort4*>(lo)[i] = L;
}

// W[K][Nn] row-major -> transposed split Wt[Nn][K] (hi, lo)
__global__ void splitT_bf16_k(const float* __restrict__ W, u16* __restrict__ thi,
                              u16* __restrict__ tlo, int K, int Nn) {
    int idx = blockIdx.x * 256 + threadIdx.x;
    if (idx >= K * Nn) return;
    int k = idx / Nn, nn = idx - k * Nn;
    float v = W[idx];
    u16 h = bf16rn(v);
    u16 l = bf16rn(v - bf16f(h));
    thi[(size_t)nn * K + k] = h;
    tlo[(size_t)nn * K + k] = l;
}

// ---------------- split-bf16 MFMA GEMM, LDS-staged A ----------------
// C[M,Nn] = (Ahi+Alo)[M,K] @ (Bhi+Blo)[K,Nn]  (lo*lo dropped, ~2^-18 rel)
// Bt* transposed [Nn][K]. Block: 64 x (NF*64) tile, 256 threads = 4 waves;
// wave wv owns cols wv*NF*16..+NF*16, all 64 rows (4 m-frags of 16).
// A tile (64 rows x 32 k, hi+lo) in LDS, k-major granules [kg][row] (16B each)
// -> staging is linear (global_load_lds) and ds_read is 2-way-bank (free).
// mfma_f32_16x16x32_bf16: A lane l = row (l&15), k=(l>>4)*8..+8;
// C/D: col = lane&15, row = (lane>>4)*4 + reg.
template <int NF>
__global__ __launch_bounds__(256) void gemm_lds_k(
        const u16* __restrict__ Ahi, const u16* __restrict__ Alo,
        const u16* __restrict__ Bthi, const u16* __restrict__ Btlo,
        float* __restrict__ C, int M, int Nn, int K) {
    __shared__ u16 Ah[2][4][64 * 8];   // [buf][kg][row*8]
    __shared__ u16 Al[2][4][64 * 8];
    const int mb = (M + 63) >> 6;
    const int mi = blockIdx.x % mb;
    const int ni = blockIdx.x / mb;
    const int m0 = mi * 64;
    const int n0 = ni * (NF * 64);
    const int wv = threadIdx.x >> 6;       // 0..3 (also: staged kg-column)
    const int lane = threadIdx.x & 63;
    const int rr = lane & 15;
    const int kg = lane >> 4;

    // staging: wave wv stages granule-column kg=wv; lane l -> row l
    int srow = m0 + lane; if (srow > M - 1) srow = M - 1;
    const u16* sh = Ahi + (size_t)srow * K + wv * 8;
    const u16* sl = Alo + (size_t)srow * K + wv * 8;

    // B pointers (per-wave cols), bf16x8 per lane
    const u16* pbh[NF];
    const u16* pbl[NF];
#pragma unroll
    for (int nf = 0; nf < NF; ++nf) {
        int col = n0 + (wv * NF + nf) * 16 + rr;
        pbh[nf] = Bthi + (size_t)col * K + kg * 8;
        pbl[nf] = Btlo + (size_t)col * K + kg * 8;
    }

    f32x4 acc[4][NF];
#pragma unroll
    for (int mf = 0; mf < 4; ++mf)
#pragma unroll
        for (int nf = 0; nf < NF; ++nf) acc[mf][nf] = (f32x4){0.f, 0.f, 0.f, 0.f};

    bf16x8 bhc[NF], blc[NF], bhn[NF], bln[NF];
#pragma unroll
    for (int nf = 0; nf < NF; ++nf) {
        bhc[nf] = *reinterpret_cast<const bf16x8*>(pbh[nf]);
        blc[nf] = *reinterpret_cast<const bf16x8*>(pbl[nf]);
    }
    gload16(sh, &Ah[0][wv][0]);
    gload16(sl, &Al[0][wv][0]);
    __syncthreads();   // drains vmcnt (staging) per HIP barrier semantics

    const int NT = K >> 5;
    for (int t = 0; t < NT; ++t) {
        const int cur = t & 1;
        if (t + 1 < NT) {
            const int kc = (t + 1) << 5;
#pragma unroll
            for (int nf = 0; nf < NF; ++nf) {
                bhn[nf] = *reinterpret_cast<const bf16x8*>(pbh[nf] + kc);
                bln[nf] = *reinterpret_cast<const bf16x8*>(pbl[nf] + kc);
            }
            gload16(sh + kc, &Ah[cur ^ 1][wv][0]);
            gload16(sl + kc, &Al[cur ^ 1][wv][0]);
        }
        bf16x8 ah[4], al[4];
#pragma unroll
        for (int mf = 0; mf < 4; ++mf) {
            ah[mf] = *reinterpret_cast<const bf16x8*>(&Ah[cur][kg][(mf * 16 + rr) * 8]);
            al[mf] = *reinterpret_cast<const bf16x8*>(&Al[cur][kg][(mf * 16 + rr) * 8]);
        }
#pragma unroll
        for (int mf = 0; mf < 4; ++mf)
#pragma unroll
            for (int nf = 0; nf < NF; ++nf) {
                acc[mf][nf] = __builtin_amdgcn_mfma_f32_16x16x32_bf16(ah[mf], bhc[nf], acc[mf][nf], 0, 0, 0);
                acc[mf][nf] = __builtin_amdgcn_mfma_f32_16x16x32_bf16(ah[mf], blc[nf], acc[mf][nf], 0, 0, 0);
                acc[mf][nf] = __builtin_amdgcn_mfma_f32_16x16x32_bf16(al[mf], bhc[nf], acc[mf][nf], 0, 0, 0);
            }
#pragma unroll
        for (int nf = 0; nf < NF; ++nf) { bhc[nf] = bhn[nf]; blc[nf] = bln[nf]; }
        __syncthreads();   // next-buf staging complete; cur buf free to overwrite
    }

#pragma unroll
    for (int mf = 0; mf < 4; ++mf)
#pragma unroll
        for (int nf = 0; nf < NF; ++nf)
#pragma unroll
            for (int rg = 0; rg < 4; ++rg) {
                int row = m0 + mf * 16 + kg * 4 + rg;
                if (row < M)
                    C[(size_t)row * Nn + n0 + (wv * NF + nf) * 16 + rr] = acc[mf][nf][rg];
            }
}

// ---------------- per-(node,head) attention scalars ----------------
__global__ void attn_scores4_k(const float* __restrict__ hin, const float* __restrict__ a_src,
                               const float* __restrict__ a_dst, float* __restrict__ esrc,
                               float* __restrict__ edst, int n) {
    int node = blockIdx.x * 4 + (threadIdx.x >> 6);
    int lane = threadIdx.x & 63;
    if (node >= n) return;
    float4 hv  = *reinterpret_cast<const float4*>(&hin[(size_t)node * 256 + lane * 4]);
    float4 asv = *reinterpret_cast<const float4*>(&a_src[lane * 4]);
    float4 adv = *reinterpret_cast<const float4*>(&a_dst[lane * 4]);
    float vs = hv.x * asv.x + hv.y * asv.y + hv.z * asv.z + hv.w * asv.w;
    float vd = hv.x * adv.x + hv.y * adv.y + hv.z * adv.z + hv.w * adv.w;
#pragma unroll
    for (int off = 8; off; off >>= 1) {
        vs += __shfl_xor(vs, off);
        vd += __shfl_xor(vd, off);
    }
    if ((lane & 15) == 0) {
        int h = lane >> 4;
        esrc[node * 4 + h] = vs;
        edst[node * 4 + h] = vd;
    }
}

__global__ void attn_scores1_k(const float* __restrict__ hin, const float* __restrict__ a_src,
                               const float* __restrict__ a_dst, float* __restrict__ esrc,
                               float* __restrict__ edst, int n) {
    int node = blockIdx.x * 4 + (threadIdx.x >> 6);
    int lane = threadIdx.x & 63;
    if (node >= n) return;
    float hv = hin[(size_t)node * 64 + lane];
    float vs = hv * a_src[lane];
    float vd = hv * a_dst[lane];
#pragma unroll
    for (int off = 32; off; off >>= 1) {
        vs += __shfl_xor(vs, off);
        vd += __shfl_xor(vd, off);
    }
    if (lane == 0) { esrc[node] = vs; edst[node] = vd; }
}

// ---------------- GAT aggregation, HEADS=4: one wave per dst node ----------
// Fused epilogue: output written as split bf16 (hi/lo) for the next MFMA GEMM.
__global__ __launch_bounds__(256) void gat_aggregate4_k(
        const float* __restrict__ hin, const float* __restrict__ esrc,
        const float* __restrict__ edst, const int* __restrict__ rowptr,
        const int* __restrict__ srcs, const float* __restrict__ bias,
        u16* __restrict__ ghi, u16* __restrict__ glo, int n) {
    int d = blockIdx.x * 4 + (threadIdx.x >> 6);
    int lane = threadIdx.x & 63;
    if (d >= n) return;
    int hh = lane >> 4;
    float ed = edst[d * 4 + hh];
    int lo = rowptr[d], hi = rowptr[d + 1];
    float4 acc = make_float4(0.f, 0.f, 0.f, 0.f);
    float den = 0.f;
    for (int base = lo; base < hi; base += 64) {
        int cnt = min(64, hi - base);
        int sv = (lane < cnt) ? srcs[base + lane] : 0;
        int s0 = __shfl(sv, 0);
        float es0 = esrc[s0 * 4 + hh];
        float4 h0 = *reinterpret_cast<const float4*>(&hin[(size_t)s0 * 256 + lane * 4]);
        float es1 = 0.f;
        float4 h1 = h0;
        if (cnt > 1) {
            int s1 = __shfl(sv, 1);
            es1 = esrc[s1 * 4 + hh];
            h1 = *reinterpret_cast<const float4*>(&hin[(size_t)s1 * 256 + lane * 4]);
        }
        for (int j = 0; j < cnt; ++j) {
            float es = es0;
            float4 hv = h0;
            es0 = es1; h0 = h1;
            if (j + 2 < cnt) {
                int s2 = __shfl(sv, j + 2);
                es1 = esrc[s2 * 4 + hh];
                h1 = *reinterpret_cast<const float4*>(&hin[(size_t)s2 * 256 + lane * 4]);
            }
            float e = es + ed;
            e = (e >= 0.f) ? e : 0.2f * e;       // leaky_relu(0.2)
            float w = __expf(e);
            den += w;
            acc.x = fmaf(w, hv.x, acc.x);
            acc.y = fmaf(w, hv.y, acc.y);
            acc.z = fmaf(w, hv.z, acc.z);
            acc.w = fmaf(w, hv.w, acc.w);
        }
    }
    float inv = 1.f / den;
    float4 bv = *reinterpret_cast<const float4*>(&bias[lane * 4]);
    float4 o;
    o.x = acc.x * inv + bv.x;
    o.y = acc.y * inv + bv.y;
    o.z = acc.z * inv + bv.z;
    o.w = acc.w * inv + bv.w;
    o.x = (o.x > 0.f) ? o.x : expm1f(o.x);       // ELU
    o.y = (o.y > 0.f) ? o.y : expm1f(o.y);
    o.z = (o.z > 0.f) ? o.z : expm1f(o.z);
    o.w = (o.w > 0.f) ? o.w : expm1f(o.w);
    u16 hx = bf16rn(o.x), hy = bf16rn(o.y), hz = bf16rn(o.z), hw = bf16rn(o.w);
    ushort4 H = make_ushort4(hx, hy, hz, hw);
    ushort4 L = make_ushort4(bf16rn(o.x - bf16f(hx)), bf16rn(o.y - bf16f(hy)),
                             bf16rn(o.z - bf16f(hz)), bf16rn(o.w - bf16f(hw)));
    *reinterpret_cast<ushort4*>(&ghi[(size_t)d * 256 + lane * 4]) = H;
    *reinterpret_cast<ushort4*>(&glo[(size_t)d * 256 + lane * 4]) = L;
}

// ---------------- layer-3 aggregate (1 head) fused with node attn gate ------
__global__ __launch_bounds__(256) void gat_aggregate1_attn_k(
        const float* __restrict__ hin, const float* __restrict__ esrc,
        const float* __restrict__ edst, const int* __restrict__ rowptr,
        const int* __restrict__ srcs, const float* __restrict__ bias,
        const float* __restrict__ wp, const float* __restrict__ bp,
        float* __restrict__ gout, float* __restrict__ attn, int n) {
    int d = blockIdx.x * 4 + (threadIdx.x >> 6);
    int lane = threadIdx.x & 63;
    if (d >= n) return;
    float ed = edst[d];
    int lo = rowptr[d], hi = rowptr[d + 1];
    float den = 0.f, acc = 0.f;
    for (int base = lo; base < hi; base += 64) {
        int cnt = min(64, hi - base);
        int sv = (lane < cnt) ? srcs[base + lane] : 0;
        int s0 = __shfl(sv, 0);
        float es_nxt = esrc[s0];
        float h_nxt = hin[(size_t)s0 * 64 + lane];
        for (int j = 0; j < cnt; ++j) {
            float es = es_nxt;
            float hv = h_nxt;
            if (j + 1 < cnt) {
                int s1 = __shfl(sv, j + 1);
                es_nxt = esrc[s1];
                h_nxt = hin[(size_t)s1 * 64 + lane];
            }
            float e = es + ed;
            e = (e >= 0.f) ? e : 0.2f * e;
            float w = __expf(e);
            den += w;
            acc = fmaf(w, hv, acc);
        }
    }
    float o = acc / den + bias[lane];
    o = (o > 0.f) ? o : expm1f(o);               // ELU
    gout[(size_t)d * 64 + lane] = o;
    float v = o * wp[lane];
#pragma unroll
    for (int off = 32; off; off >>= 1) v += __shfl_xor(v, off);
    if (lane == 0) attn[d] = 1.f / (1.f + __expf(-(v + bp[0])));
}

// ---------------- parallel segmented pooling (batch is sorted) --------------
__global__ void pool_partial_k(const float* __restrict__ g3, const float* __restrict__ attn,
                               const int* __restrict__ batch, int n, float* __restrict__ sums) {
    int wid = blockIdx.x * (blockDim.x >> 6) + (threadIdx.x >> 6);
    int lane = threadIdx.x & 63;
    int nwaves = gridDim.x * (blockDim.x >> 6);
    int per = (n + nwaves - 1) / nwaves;
    int i0 = wid * per;
    int i1 = i0 + per;
    if (i1 > n) i1 = n;
    if (i0 >= i1) return;
    int cur = batch[i0];
    float acc = 0.f;
    for (int i = i0; i < i1; ++i) {
        int b = batch[i];
        if (b != cur) {
            atomicAdd(&sums[cur * 64 + lane], acc);
            acc = 0.f;
            cur = b;
        }
        acc += g3[(size_t)i * 64 + lane] * attn[i];
    }
    atomicAdd(&sums[cur * 64 + lane], acc);
}

// ---------------- final regressor: one block, wave per graph ----------------
__global__ void regress_k(const float* __restrict__ sums, const int* __restrict__ batch, int n,
                          const float* __restrict__ wr, const float* __restrict__ br,
                          float* __restrict__ out, int B) {
    int b = threadIdx.x >> 6;
    int lane = threadIdx.x & 63;
    if (b >= B) return;
    int lo = 0, hi = n;
    while (lo < hi) { int mid = (lo + hi) >> 1; if (batch[mid] < b) lo = mid + 1; else hi = mid; }
    int seg_lo = lo;
    lo = 0; hi = n;
    while (lo < hi) { int mid = (lo + hi) >> 1; if (batch[mid] < b + 1) lo = mid + 1; else hi = mid; }
    float cnt = (float)(lo - seg_lo);
    if (cnt < 1.f) cnt = 1.f;
    float v = (sums[b * 64 + lane] / cnt) * wr[lane];
#pragma unroll
    for (int off = 32; off; off >>= 1) v += __shfl_xor(v, off);
    if (lane == 0) out[b] = v + br[0];
}

// ---------------------------------------------------------------------------
extern "C" void kernel_launch(void* const* d_in, const int* in_sizes, int n_in,
                              void* d_out, int out_size, void* d_ws, size_t ws_size,
                              hipStream_t stream) {
    const float* x   = (const float*)d_in[0];
    const int*   ei  = (const int*)d_in[1];
    const int*   bat = (const int*)d_in[2];
    const float* W1  = (const float*)d_in[3];
    const float* as1 = (const float*)d_in[4];
    const float* ad1 = (const float*)d_in[5];
    const float* b1  = (const float*)d_in[6];
    const float* W2  = (const float*)d_in[7];
    const float* as2 = (const float*)d_in[8];
    const float* ad2 = (const float*)d_in[9];
    const float* b2  = (const float*)d_in[10];
    const float* W3  = (const float*)d_in[11];
    const float* as3 = (const float*)d_in[12];
    const float* ad3 = (const float*)d_in[13];
    const float* b3  = (const float*)d_in[14];
    const float* wp  = (const float*)d_in[15];
    const float* bp  = (const float*)d_in[16];
    const float* wr  = (const float*)d_in[17];
    const float* br  = (const float*)d_in[18];
    float* out = (float*)d_out;

    const int N    = in_sizes[2];          // 20000
    const int E    = in_sizes[1] / 2;      // 320000
    const int DIN  = in_sizes[0] / N;      // 128
    const int Etot = E + N;
    const int Bc   = out_size;             // 16

    char* ws = (char*)d_ws;
    size_t off = 0;
    auto alloc = [&](size_t bytes) {
        void* p = ws + off;
        off = (off + bytes + 255) & ~(size_t)255;
        return p;
    };
    int*   deg    = (int*)alloc((size_t)N * 4);
    int*   rowptr = (int*)alloc((size_t)(N + 1) * 4);
    int*   cursor = (int*)alloc((size_t)N * 4);
    int*   srcs   = (int*)alloc((size_t)Etot * 4);
    float* bufA   = (float*)alloc((size_t)N * 256 * 4);     // GEMM out h (f32)
    u16*   Ahi    = (u16*)alloc((size_t)N * 256 * 2);       // x/g split hi
    u16*   Alo    = (u16*)alloc((size_t)N * 256 * 2);       // x/g split lo
    float* h3     = (float*)alloc((size_t)N * 64 * 4);
    float* g3     = (float*)alloc((size_t)N * 64 * 4);
    float* esrc   = (float*)alloc((size_t)N * 4 * 4);
    float* edst   = (float*)alloc((size_t)N * 4 * 4);
    float* attn   = (float*)alloc((size_t)N * 4);
    float* sums   = (float*)alloc((size_t)Bc * 64 * 4);
    u16*   w1hi   = (u16*)alloc((size_t)256 * DIN * 2);
    u16*   w1lo   = (u16*)alloc((size_t)256 * DIN * 2);
    u16*   w2hi   = (u16*)alloc((size_t)256 * 256 * 2);
    u16*   w2lo   = (u16*)alloc((size_t)256 * 256 * 2);
    u16*   w3hi   = (u16*)alloc((size_t)64 * 256 * 2);
    u16*   w3lo   = (u16*)alloc((size_t)64 * 256 * 2);
    (void)ws_size;

    // CSR build (shared by all layers)
    hipMemsetAsync(deg, 0, (size_t)N * 4, stream);
    int eb = (Etot + 255) / 256;
    edge_hist_k<<<eb, 256, 0, stream>>>(ei, E, N, deg);
    scan_excl_k<<<1, 1024, 0, stream>>>(deg, rowptr, cursor, N);
    edge_scatter_k<<<eb, 256, 0, stream>>>(ei, E, N, cursor, srcs);

    // weight splits (transposed) + x split
    splitT_bf16_k<<<(DIN * 256 + 255) / 256, 256, 0, stream>>>(W1, w1hi, w1lo, DIN, 256);
    splitT_bf16_k<<<(256 * 256 + 255) / 256, 256, 0, stream>>>(W2, w2hi, w2lo, 256, 256);
    splitT_bf16_k<<<(256 * 64 + 255) / 256, 256, 0, stream>>>(W3, w3hi, w3lo, 256, 64);
    split_bf16_k<<<(N * DIN / 4 + 255) / 256, 256, 0, stream>>>(x, Ahi, Alo, N * DIN / 4);

    const int mb = (N + 63) / 64;          // 313
    int nb4 = (N + 3) / 4;

    // Layer 1: DIN -> (4,64) concat      (BN=128 -> 2 n-tiles)
    gemm_lds_k<2><<<mb * 2, 256, 0, stream>>>(Ahi, Alo, w1hi, w1lo, bufA, N, 256, DIN);
    attn_scores4_k<<<nb4, 256, 0, stream>>>(bufA, as1, ad1, esrc, edst, N);
    gat_aggregate4_k<<<nb4, 256, 0, stream>>>(bufA, esrc, edst, rowptr, srcs, b1, Ahi, Alo, N);

    // Layer 2: 256 -> (4,64) concat
    gemm_lds_k<2><<<mb * 2, 256, 0, stream>>>(Ahi, Alo, w2hi, w2lo, bufA, N, 256, 256);
    attn_scores4_k<<<nb4, 256, 0, stream>>>(bufA, as2, ad2, esrc, edst, N);
    gat_aggregate4_k<<<nb4, 256, 0, stream>>>(bufA, esrc, edst, rowptr, srcs, b2, Ahi, Alo, N);

    // Layer 3: 256 -> (1,64) mean + fused node-attention gate   (BN=64)
    gemm_lds_k<1><<<mb, 256, 0, stream>>>(Ahi, Alo, w3hi, w3lo, h3, N, 64, 256);
    attn_scores1_k<<<nb4, 256, 0, stream>>>(h3, as3, ad3, esrc, edst, N);
    gat_aggregate1_attn_k<<<nb4, 256, 0, stream>>>(h3, esrc, edst, rowptr, srcs, b3, wp, bp, g3, attn, N);

    // Attention pool + regressor (parallel)
    hipMemsetAsync(sums, 0, (size_t)Bc * 64 * 4, stream);
    pool_partial_k<<<256, 256, 0, stream>>>(g3, attn, bat, N, sums);
    regress_k<<<1, 1024, 0, stream>>>(sums, bat, N, wr, br, out, Bc);
}

// Round 7
// 281.483 us; speedup vs baseline: 1.6060x; 1.0594x over previous
//
#include <hip/hip_runtime.h>

// ---------------------------------------------------------------------------
// GAT (3 layers) + attention pooling + regressor.
// GEMMs: split-bf16 MFMA (a_hi+a_lo, 3 products, f32 accum), A staged in LDS
// via global_load_lds (k-major granules), B reg-prefetched from L2.
// Aggregates: batched edge weights (1 exp per 16 edges), 4-deep row prefetch.
// N=20000 nodes, E=320000 edges (+N self loops), H=4 heads, C=64, B=16 graphs.
// ---------------------------------------------------------------------------

typedef unsigned short u16;
typedef __attribute__((ext_vector_type(8))) short bf16x8;
typedef __attribute__((ext_vector_type(4))) float f32x4;

__device__ __forceinline__ u16 bf16rn(float x) {
    unsigned u = __float_as_uint(x);
    u += 0x7FFFu + ((u >> 16) & 1u);
    return (u16)(u >> 16);
}
__device__ __forceinline__ float bf16f(u16 h) {
    return __uint_as_float(((unsigned)h) << 16);
}

__device__ __forceinline__ void gload16(const u16* g, u16* l) {
    __builtin_amdgcn_global_load_lds(
        (const __attribute__((address_space(1))) unsigned int*)g,
        (__attribute__((address_space(3))) unsigned int*)l, 16, 0, 0);
}

// ---------------- CSR-by-destination build ----------------
__global__ void edge_hist_k(const int* __restrict__ ei, int E, int n, int* __restrict__ deg) {
    int i = blockIdx.x * blockDim.x + threadIdx.x;
    if (i >= E + n) return;
    int dst = (i < E) ? ei[E + i] : (i - E);   // self-loop for i >= E
    atomicAdd(&deg[dst], 1);
}

__global__ __launch_bounds__(1024) void scan_excl_k(const int* __restrict__ deg, int* __restrict__ rowptr,
                                                    int* __restrict__ cursor, int n) {
    __shared__ int part[1024];
    int tid = threadIdx.x;
    int chunk = (n + 1023) / 1024;
    int lo = tid * chunk;
    int hi = lo + chunk;
    if (lo > n) lo = n;
    if (hi > n) hi = n;
    int s = 0;
    for (int i = lo; i < hi; ++i) s += deg[i];
    part[tid] = s;
    __syncthreads();
    for (int off = 1; off < 1024; off <<= 1) {
        int v = (tid >= off) ? part[tid - off] : 0;
        __syncthreads();
        part[tid] += v;
        __syncthreads();
    }
    int run = (tid == 0) ? 0 : part[tid - 1];
    for (int i = lo; i < hi; ++i) {
        rowptr[i] = run;
        cursor[i] = run;
        run += deg[i];
    }
    if (tid == 1023) rowptr[n] = run;
}

__global__ void edge_scatter_k(const int* __restrict__ ei, int E, int n,
                               int* __restrict__ cursor, int* __restrict__ srcs) {
    int i = blockIdx.x * blockDim.x + threadIdx.x;
    if (i >= E + n) return;
    int src, dst;
    if (i < E) { src = ei[i]; dst = ei[E + i]; }
    else       { src = i - E; dst = src; }
    int pos = atomicAdd(&cursor[dst], 1);
    srcs[pos] = src;
}

// ---------------- bf16 split conversions ----------------
__global__ void split_bf16_k(const float* __restrict__ in, u16* __restrict__ hi,
                             u16* __restrict__ lo, int n4) {
    int i = blockIdx.x * 256 + threadIdx.x;
    if (i >= n4) return;
    float4 v = reinterpret_cast<const float4*>(in)[i];
    u16 hx = bf16rn(v.x), hy = bf16rn(v.y), hz = bf16rn(v.z), hw = bf16rn(v.w);
    ushort4 H = make_ushort4(hx, hy, hz, hw);
    ushort4 L = make_ushort4(bf16rn(v.x - bf16f(hx)), bf16rn(v.y - bf16f(hy)),
                             bf16rn(v.z - bf16f(hz)), bf16rn(v.w - bf16f(hw)));
    reinterpret_cast<ushort4*>(hi)[i] = H;
    reinterpret_cast<ushort4*>(lo)[i] = L;
}

// W[K][Nn] row-major -> transposed split Wt[Nn][K] (hi, lo)
__global__ void splitT_bf16_k(const float* __restrict__ W, u16* __restrict__ thi,
                              u16* __restrict__ tlo, int K, int Nn) {
    int idx = blockIdx.x * 256 + threadIdx.x;
    if (idx >= K * Nn) return;
    int k = idx / Nn, nn = idx - k * Nn;
    float v = W[idx];
    u16 h = bf16rn(v);
    u16 l = bf16rn(v - bf16f(h));
    thi[(size_t)nn * K + k] = h;
    tlo[(size_t)nn * K + k] = l;
}

// ---------------- split-bf16 MFMA GEMM, LDS-staged A ----------------
template <int NF>
__global__ __launch_bounds__(256) void gemm_lds_k(
        const u16* __restrict__ Ahi, const u16* __restrict__ Alo,
        const u16* __restrict__ Bthi, const u16* __restrict__ Btlo,
        float* __restrict__ C, int M, int Nn, int K) {
    __shared__ u16 Ah[2][4][64 * 8];   // [buf][kg][row*8]
    __shared__ u16 Al[2][4][64 * 8];
    const int mb = (M + 63) >> 6;
    const int mi = blockIdx.x % mb;
    const int ni = blockIdx.x / mb;
    const int m0 = mi * 64;
    const int n0 = ni * (NF * 64);
    const int wv = threadIdx.x >> 6;       // 0..3 (also: staged kg-column)
    const int lane = threadIdx.x & 63;
    const int rr = lane & 15;
    const int kg = lane >> 4;

    int srow = m0 + lane; if (srow > M - 1) srow = M - 1;
    const u16* sh = Ahi + (size_t)srow * K + wv * 8;
    const u16* sl = Alo + (size_t)srow * K + wv * 8;

    const u16* pbh[NF];
    const u16* pbl[NF];
#pragma unroll
    for (int nf = 0; nf < NF; ++nf) {
        int col = n0 + (wv * NF + nf) * 16 + rr;
        pbh[nf] = Bthi + (size_t)col * K + kg * 8;
        pbl[nf] = Btlo + (size_t)col * K + kg * 8;
    }

    f32x4 acc[4][NF];
#pragma unroll
    for (int mf = 0; mf < 4; ++mf)
#pragma unroll
        for (int nf = 0; nf < NF; ++nf) acc[mf][nf] = (f32x4){0.f, 0.f, 0.f, 0.f};

    bf16x8 bhc[NF], blc[NF], bhn[NF], bln[NF];
#pragma unroll
    for (int nf = 0; nf < NF; ++nf) {
        bhc[nf] = *reinterpret_cast<const bf16x8*>(pbh[nf]);
        blc[nf] = *reinterpret_cast<const bf16x8*>(pbl[nf]);
    }
    gload16(sh, &Ah[0][wv][0]);
    gload16(sl, &Al[0][wv][0]);
    __syncthreads();

    const int NT = K >> 5;
    for (int t = 0; t < NT; ++t) {
        const int cur = t & 1;
        if (t + 1 < NT) {
            const int kc = (t + 1) << 5;
#pragma unroll
            for (int nf = 0; nf < NF; ++nf) {
                bhn[nf] = *reinterpret_cast<const bf16x8*>(pbh[nf] + kc);
                bln[nf] = *reinterpret_cast<const bf16x8*>(pbl[nf] + kc);
            }
            gload16(sh + kc, &Ah[cur ^ 1][wv][0]);
            gload16(sl + kc, &Al[cur ^ 1][wv][0]);
        }
        bf16x8 ah[4], al[4];
#pragma unroll
        for (int mf = 0; mf < 4; ++mf) {
            ah[mf] = *reinterpret_cast<const bf16x8*>(&Ah[cur][kg][(mf * 16 + rr) * 8]);
            al[mf] = *reinterpret_cast<const bf16x8*>(&Al[cur][kg][(mf * 16 + rr) * 8]);
        }
#pragma unroll
        for (int mf = 0; mf < 4; ++mf)
#pragma unroll
            for (int nf = 0; nf < NF; ++nf) {
                acc[mf][nf] = __builtin_amdgcn_mfma_f32_16x16x32_bf16(ah[mf], bhc[nf], acc[mf][nf], 0, 0, 0);
                acc[mf][nf] = __builtin_amdgcn_mfma_f32_16x16x32_bf16(ah[mf], blc[nf], acc[mf][nf], 0, 0, 0);
                acc[mf][nf] = __builtin_amdgcn_mfma_f32_16x16x32_bf16(al[mf], bhc[nf], acc[mf][nf], 0, 0, 0);
            }
#pragma unroll
        for (int nf = 0; nf < NF; ++nf) { bhc[nf] = bhn[nf]; blc[nf] = bln[nf]; }
        __syncthreads();
    }

#pragma unroll
    for (int mf = 0; mf < 4; ++mf)
#pragma unroll
        for (int nf = 0; nf < NF; ++nf)
#pragma unroll
            for (int rg = 0; rg < 4; ++rg) {
                int row = m0 + mf * 16 + kg * 4 + rg;
                if (row < M)
                    C[(size_t)row * Nn + n0 + (wv * NF + nf) * 16 + rr] = acc[mf][nf][rg];
            }
}

// ---------------- per-(node,head) attention scalars ----------------
__global__ void attn_scores4_k(const float* __restrict__ hin, const float* __restrict__ a_src,
                               const float* __restrict__ a_dst, float* __restrict__ esrc,
                               float* __restrict__ edst, int n) {
    int node = blockIdx.x * 4 + (threadIdx.x >> 6);
    int lane = threadIdx.x & 63;
    if (node >= n) return;
    float4 hv  = *reinterpret_cast<const float4*>(&hin[(size_t)node * 256 + lane * 4]);
    float4 asv = *reinterpret_cast<const float4*>(&a_src[lane * 4]);
    float4 adv = *reinterpret_cast<const float4*>(&a_dst[lane * 4]);
    float vs = hv.x * asv.x + hv.y * asv.y + hv.z * asv.z + hv.w * asv.w;
    float vd = hv.x * adv.x + hv.y * adv.y + hv.z * adv.z + hv.w * adv.w;
#pragma unroll
    for (int off = 8; off; off >>= 1) {
        vs += __shfl_xor(vs, off);
        vd += __shfl_xor(vd, off);
    }
    if ((lane & 15) == 0) {
        int h = lane >> 4;
        esrc[node * 4 + h] = vs;
        edst[node * 4 + h] = vd;
    }
}

__global__ void attn_scores1_k(const float* __restrict__ hin, const float* __restrict__ a_src,
                               const float* __restrict__ a_dst, float* __restrict__ esrc,
                               float* __restrict__ edst, int n) {
    int node = blockIdx.x * 4 + (threadIdx.x >> 6);
    int lane = threadIdx.x & 63;
    if (node >= n) return;
    float hv = hin[(size_t)node * 64 + lane];
    float vs = hv * a_src[lane];
    float vd = hv * a_dst[lane];
#pragma unroll
    for (int off = 32; off; off >>= 1) {
        vs += __shfl_xor(vs, off);
        vd += __shfl_xor(vd, off);
    }
    if (lane == 0) { esrc[node] = vs; edst[node] = vd; }
}

// ---------------- GAT aggregation, HEADS=4: one wave per dst node ----------
// Weights batched: per 32-edge chunk, lane (jj,hh) computes w(edge jj, head hh)
// with ONE vector exp covering 16 edges x 4 heads. Multiply loop: shfl(w) +
// float4 row (4-deep prefetch, named regs) + 4 fma per edge. Tail edges have
// w==0 and clamped (valid) addresses, so the quad loop needs no guards.
__global__ __launch_bounds__(256) void gat_aggregate4_k(
        const float* __restrict__ hin, const float* __restrict__ esrc,
        const float* __restrict__ edst, const int* __restrict__ rowptr,
        const int* __restrict__ srcs, const float* __restrict__ bias,
        u16* __restrict__ ghi, u16* __restrict__ glo, int n) {
    int d = blockIdx.x * 4 + (threadIdx.x >> 6);
    int lane = threadIdx.x & 63;
    if (d >= n) return;
    const int hh = lane >> 4;
    const int jj = lane & 15;
    float ed = edst[d * 4 + hh];
    int lo = rowptr[d], hi = rowptr[d + 1];
    float4 acc = make_float4(0.f, 0.f, 0.f, 0.f);
    float den = 0.f;
    for (int base = lo; base < hi; base += 32) {
        int cnt = min(32, hi - base);
        // --- batched weights for up to 32 edges ---
        int i0 = base + jj, i1 = base + 16 + jj;
        int s0 = srcs[(i0 < hi) ? i0 : lo];
        int s1 = srcs[(i1 < hi) ? i1 : lo];
        float e0 = esrc[s0 * 4 + hh] + ed;
        e0 = (e0 >= 0.f) ? e0 : 0.2f * e0;
        float w0 = (jj < cnt) ? __expf(e0) : 0.f;
        float e1 = esrc[s1 * 4 + hh] + ed;
        e1 = (e1 >= 0.f) ? e1 : 0.2f * e1;
        float w1 = (jj + 16 < cnt) ? __expf(e1) : 0.f;
        float ws = w0 + w1;
#pragma unroll
        for (int off = 1; off < 16; off <<= 1) ws += __shfl_xor(ws, off);
        den += ws;
        // --- multiply, 4-deep prefetch ---
        auto loadrow = [&](int j) -> float4 {
            j = (j < cnt) ? j : (cnt - 1);
            int sp = __shfl((j < 16) ? s0 : s1, j & 15);
            return *reinterpret_cast<const float4*>(&hin[(size_t)sp * 256 + lane * 4]);
        };
        auto wsel = [&](int j) -> float {
            return __shfl((j < 16) ? w0 : w1, (lane & 48) | (j & 15));
        };
        float4 p0 = loadrow(0), p1 = loadrow(1), p2 = loadrow(2), p3 = loadrow(3);
        for (int j = 0; j < cnt; j += 4) {
            float4 q0 = p0, q1 = p1, q2 = p2, q3 = p3;
            p0 = loadrow(j + 4);
            p1 = loadrow(j + 5);
            p2 = loadrow(j + 6);
            p3 = loadrow(j + 7);
            float wA = wsel(j), wB = wsel(j + 1), wC = wsel(j + 2), wD = wsel(j + 3);
            acc.x = fmaf(wA, q0.x, acc.x); acc.y = fmaf(wA, q0.y, acc.y);
            acc.z = fmaf(wA, q0.z, acc.z); acc.w = fmaf(wA, q0.w, acc.w);
            acc.x = fmaf(wB, q1.x, acc.x); acc.y = fmaf(wB, q1.y, acc.y);
            acc.z = fmaf(wB, q1.z, acc.z); acc.w = fmaf(wB, q1.w, acc.w);
            acc.x = fmaf(wC, q2.x, acc.x); acc.y = fmaf(wC, q2.y, acc.y);
            acc.z = fmaf(wC, q2.z, acc.z); acc.w = fmaf(wC, q2.w, acc.w);
            acc.x = fmaf(wD, q3.x, acc.x); acc.y = fmaf(wD, q3.y, acc.y);
            acc.z = fmaf(wD, q3.z, acc.z); acc.w = fmaf(wD, q3.w, acc.w);
        }
    }
    float inv = 1.f / den;
    float4 bv = *reinterpret_cast<const float4*>(&bias[lane * 4]);
    float4 o;
    o.x = acc.x * inv + bv.x;
    o.y = acc.y * inv + bv.y;
    o.z = acc.z * inv + bv.z;
    o.w = acc.w * inv + bv.w;
    o.x = (o.x > 0.f) ? o.x : expm1f(o.x);       // ELU
    o.y = (o.y > 0.f) ? o.y : expm1f(o.y);
    o.z = (o.z > 0.f) ? o.z : expm1f(o.z);
    o.w = (o.w > 0.f) ? o.w : expm1f(o.w);
    u16 hx = bf16rn(o.x), hy = bf16rn(o.y), hz = bf16rn(o.z), hw = bf16rn(o.w);
    ushort4 H = make_ushort4(hx, hy, hz, hw);
    ushort4 L = make_ushort4(bf16rn(o.x - bf16f(hx)), bf16rn(o.y - bf16f(hy)),
                             bf16rn(o.z - bf16f(hz)), bf16rn(o.w - bf16f(hw)));
    *reinterpret_cast<ushort4*>(&ghi[(size_t)d * 256 + lane * 4]) = H;
    *reinterpret_cast<ushort4*>(&glo[(size_t)d * 256 + lane * 4]) = L;
}

// ---------------- layer-3 aggregate (1 head) fused with node attn gate ------
// Batched weights: one vector exp covers 64 edges; 4-deep scalar-row prefetch.
__global__ __launch_bounds__(256) void gat_aggregate1_attn_k(
        const float* __restrict__ hin, const float* __restrict__ esrc,
        const float* __restrict__ edst, const int* __restrict__ rowptr,
        const int* __restrict__ srcs, const float* __restrict__ bias,
        const float* __restrict__ wp, const float* __restrict__ bp,
        float* __restrict__ gout, float* __restrict__ attn, int n) {
    int d = blockIdx.x * 4 + (threadIdx.x >> 6);
    int lane = threadIdx.x & 63;
    if (d >= n) return;
    float ed = edst[d];
    int lo = rowptr[d], hi = rowptr[d + 1];
    float den = 0.f, acc = 0.f;
    for (int base = lo; base < hi; base += 64) {
        int cnt = min(64, hi - base);
        int idx = base + lane;
        int s = srcs[(idx < hi) ? idx : lo];
        float e = esrc[s] + ed;
        e = (e >= 0.f) ? e : 0.2f * e;
        float w = (lane < cnt) ? __expf(e) : 0.f;
        float ws = w;
#pragma unroll
        for (int off = 1; off < 64; off <<= 1) ws += __shfl_xor(ws, off);
        den += ws;
        auto loadrow = [&](int j) -> float {
            j = (j < cnt) ? j : (cnt - 1);
            int sp = __shfl(s, j);
            return hin[(size_t)sp * 64 + lane];
        };
        float p0 = loadrow(0), p1 = loadrow(1), p2 = loadrow(2), p3 = loadrow(3);
        for (int j = 0; j < cnt; j += 4) {
            float q0 = p0, q1 = p1, q2 = p2, q3 = p3;
            p0 = loadrow(j + 4);
            p1 = loadrow(j + 5);
            p2 = loadrow(j + 6);
            p3 = loadrow(j + 7);
            acc = fmaf(__shfl(w, j), q0, acc);
            acc = fmaf(__shfl(w, j + 1), q1, acc);
            acc = fmaf(__shfl(w, j + 2), q2, acc);
            acc = fmaf(__shfl(w, j + 3), q3, acc);
        }
    }
    float o = acc / den + bias[lane];
    o = (o > 0.f) ? o : expm1f(o);               // ELU
    gout[(size_t)d * 64 + lane] = o;
    float v = o * wp[lane];
#pragma unroll
    for (int off = 32; off; off >>= 1) v += __shfl_xor(v, off);
    if (lane == 0) attn[d] = 1.f / (1.f + __expf(-(v + bp[0])));
}

// ---------------- parallel segmented pooling (batch is sorted) --------------
__global__ void pool_partial_k(const float* __restrict__ g3, const float* __restrict__ attn,
                               const int* __restrict__ batch, int n, float* __restrict__ sums) {
    int wid = blockIdx.x * (blockDim.x >> 6) + (threadIdx.x >> 6);
    int lane = threadIdx.x & 63;
    int nwaves = gridDim.x * (blockDim.x >> 6);
    int per = (n + nwaves - 1) / nwaves;
    int i0 = wid * per;
    int i1 = i0 + per;
    if (i1 > n) i1 = n;
    if (i0 >= i1) return;
    int cur = batch[i0];
    float acc = 0.f;
    for (int i = i0; i < i1; ++i) {
        int b = batch[i];
        if (b != cur) {
            atomicAdd(&sums[cur * 64 + lane], acc);
            acc = 0.f;
            cur = b;
        }
        acc += g3[(size_t)i * 64 + lane] * attn[i];
    }
    atomicAdd(&sums[cur * 64 + lane], acc);
}

// ---------------- final regressor: one block, wave per graph ----------------
__global__ void regress_k(const float* __restrict__ sums, const int* __restrict__ batch, int n,
                          const float* __restrict__ wr, const float* __restrict__ br,
                          float* __restrict__ out, int B) {
    int b = threadIdx.x >> 6;
    int lane = threadIdx.x & 63;
    if (b >= B) return;
    int lo = 0, hi = n;
    while (lo < hi) { int mid = (lo + hi) >> 1; if (batch[mid] < b) lo = mid + 1; else hi = mid; }
    int seg_lo = lo;
    lo = 0; hi = n;
    while (lo < hi) { int mid = (lo + hi) >> 1; if (batch[mid] < b + 1) lo = mid + 1; else hi = mid; }
    float cnt = (float)(lo - seg_lo);
    if (cnt < 1.f) cnt = 1.f;
    float v = (sums[b * 64 + lane] / cnt) * wr[lane];
#pragma unroll
    for (int off = 32; off; off >>= 1) v += __shfl_xor(v, off);
    if (lane == 0) out[b] = v + br[0];
}

// ---------------------------------------------------------------------------
extern "C" void kernel_launch(void* const* d_in, const int* in_sizes, int n_in,
                              void* d_out, int out_size, void* d_ws, size_t ws_size,
                              hipStream_t stream) {
    const float* x   = (const float*)d_in[0];
    const int*   ei  = (const int*)d_in[1];
    const int*   bat = (const int*)d_in[2];
    const float* W1  = (const float*)d_in[3];
    const float* as1 = (const float*)d_in[4];
    const float* ad1 = (const float*)d_in[5];
    const float* b1  = (const float*)d_in[6];
    const float* W2  = (const float*)d_in[7];
    const float* as2 = (const float*)d_in[8];
    const float* ad2 = (const float*)d_in[9];
    const float* b2  = (const float*)d_in[10];
    const float* W3  = (const float*)d_in[11];
    const float* as3 = (const float*)d_in[12];
    const float* ad3 = (const float*)d_in[13];
    const float* b3  = (const float*)d_in[14];
    const float* wp  = (const float*)d_in[15];
    const float* bp  = (const float*)d_in[16];
    const float* wr  = (const float*)d_in[17];
    const float* br  = (const float*)d_in[18];
    float* out = (float*)d_out;

    const int N    = in_sizes[2];          // 20000
    const int E    = in_sizes[1] / 2;      // 320000
    const int DIN  = in_sizes[0] / N;      // 128
    const int Etot = E + N;
    const int Bc   = out_size;             // 16

    char* ws = (char*)d_ws;
    size_t off = 0;
    auto alloc = [&](size_t bytes) {
        void* p = ws + off;
        off = (off + bytes + 255) & ~(size_t)255;
        return p;
    };
    int*   deg    = (int*)alloc((size_t)N * 4);
    int*   rowptr = (int*)alloc((size_t)(N + 1) * 4);
    int*   cursor = (int*)alloc((size_t)N * 4);
    int*   srcs   = (int*)alloc((size_t)Etot * 4);
    float* bufA   = (float*)alloc((size_t)N * 256 * 4);     // GEMM out h (f32)
    u16*   Ahi    = (u16*)alloc((size_t)N * 256 * 2);       // x/g split hi
    u16*   Alo    = (u16*)alloc((size_t)N * 256 * 2);       // x/g split lo
    float* h3     = (float*)alloc((size_t)N * 64 * 4);
    float* g3     = (float*)alloc((size_t)N * 64 * 4);
    float* esrc   = (float*)alloc((size_t)N * 4 * 4);
    float* edst   = (float*)alloc((size_t)N * 4 * 4);
    float* attn   = (float*)alloc((size_t)N * 4);
    float* sums   = (float*)alloc((size_t)Bc * 64 * 4);
    u16*   w1hi   = (u16*)alloc((size_t)256 * DIN * 2);
    u16*   w1lo   = (u16*)alloc((size_t)256 * DIN * 2);
    u16*   w2hi   = (u16*)alloc((size_t)256 * 256 * 2);
    u16*   w2lo   = (u16*)alloc((size_t)256 * 256 * 2);
    u16*   w3hi   = (u16*)alloc((size_t)64 * 256 * 2);
    u16*   w3lo   = (u16*)alloc((size_t)64 * 256 * 2);
    (void)ws_size;

    // CSR build (shared by all layers)
    hipMemsetAsync(deg, 0, (size_t)N * 4, stream);
    int eb = (Etot + 255) / 256;
    edge_hist_k<<<eb, 256, 0, stream>>>(ei, E, N, deg);
    scan_excl_k<<<1, 1024, 0, stream>>>(deg, rowptr, cursor, N);
    edge_scatter_k<<<eb, 256, 0, stream>>>(ei, E, N, cursor, srcs);

    // weight splits (transposed) + x split
    splitT_bf16_k<<<(DIN * 256 + 255) / 256, 256, 0, stream>>>(W1, w1hi, w1lo, DIN, 256);
    splitT_bf16_k<<<(256 * 256 + 255) / 256, 256, 0, stream>>>(W2, w2hi, w2lo, 256, 256);
    splitT_bf16_k<<<(256 * 64 + 255) / 256, 256, 0, stream>>>(W3, w3hi, w3lo, 256, 64);
    split_bf16_k<<<(N * DIN / 4 + 255) / 256, 256, 0, stream>>>(x, Ahi, Alo, N * DIN / 4);

    const int mb = (N + 63) / 64;          // 313
    int nb4 = (N + 3) / 4;

    // Layer 1: DIN -> (4,64) concat      (BN=128 -> 2 n-tiles)
    gemm_lds_k<2><<<mb * 2, 256, 0, stream>>>(Ahi, Alo, w1hi, w1lo, bufA, N, 256, DIN);
    attn_scores4_k<<<nb4, 256, 0, stream>>>(bufA, as1, ad1, esrc, edst, N);
    gat_aggregate4_k<<<nb4, 256, 0, stream>>>(bufA, esrc, edst, rowptr, srcs, b1, Ahi, Alo, N);

    // Layer 2: 256 -> (4,64) concat
    gemm_lds_k<2><<<mb * 2, 256, 0, stream>>>(Ahi, Alo, w2hi, w2lo, bufA, N, 256, 256);
    attn_scores4_k<<<nb4, 256, 0, stream>>>(bufA, as2, ad2, esrc, edst, N);
    gat_aggregate4_k<<<nb4, 256, 0, stream>>>(bufA, esrc, edst, rowptr, srcs, b2, Ahi, Alo, N);

    // Layer 3: 256 -> (1,64) mean + fused node-attention gate   (BN=64)
    gemm_lds_k<1><<<mb, 256, 0, stream>>>(Ahi, Alo, w3hi, w3lo, h3, N, 64, 256);
    attn_scores1_k<<<nb4, 256, 0, stream>>>(h3, as3, ad3, esrc, edst, N);
    gat_aggregate1_attn_k<<<nb4, 256, 0, stream>>>(h3, esrc, edst, rowptr, srcs, b3, wp, bp, g3, attn, N);

    // Attention pool + regressor (parallel)
    hipMemsetAsync(sums, 0, (size_t)Bc * 64 * 4, stream);
    pool_partial_k<<<256, 256, 0, stream>>>(g3, attn, bat, N, sums);
    regress_k<<<1, 1024, 0, stream>>>(sums, bat, N, wr, br, out, Bc);
}

// Round 8
// 277.335 us; speedup vs baseline: 1.6300x; 1.0150x over previous
//
#include <hip/hip_runtime.h>

// ---------------------------------------------------------------------------
// GAT (3 layers) + attention pooling + regressor.
// GEMMs: split-bf16 MFMA (a_hi+a_lo, 3 products, f32 accum), A staged in LDS
// via global_load_lds; attn scores (e_src/e_dst) fused into GEMM epilogue.
// Aggregates: batched edge weights + 8-deep row prefetch.
// N=20000 nodes, E=320000 edges (+N self loops), H=4 heads, C=64, B=16 graphs.
// ---------------------------------------------------------------------------

typedef unsigned short u16;
typedef __attribute__((ext_vector_type(8))) short bf16x8;
typedef __attribute__((ext_vector_type(4))) float f32x4;

__device__ __forceinline__ u16 bf16rn(float x) {
    unsigned u = __float_as_uint(x);
    u += 0x7FFFu + ((u >> 16) & 1u);
    return (u16)(u >> 16);
}
__device__ __forceinline__ float bf16f(u16 h) {
    return __uint_as_float(((unsigned)h) << 16);
}

__device__ __forceinline__ void gload16(const u16* g, u16* l) {
    __builtin_amdgcn_global_load_lds(
        (const __attribute__((address_space(1))) unsigned int*)g,
        (__attribute__((address_space(3))) unsigned int*)l, 16, 0, 0);
}

// ---------------- CSR-by-destination build ----------------
__global__ void edge_hist_k(const int* __restrict__ ei, int E, int n, int* __restrict__ deg) {
    int i = blockIdx.x * blockDim.x + threadIdx.x;
    if (i >= E + n) return;
    int dst = (i < E) ? ei[E + i] : (i - E);   // self-loop for i >= E
    atomicAdd(&deg[dst], 1);
}

__global__ __launch_bounds__(1024) void scan_excl_k(const int* __restrict__ deg, int* __restrict__ rowptr,
                                                    int* __restrict__ cursor, int n) {
    __shared__ int part[1024];
    int tid = threadIdx.x;
    int chunk = (n + 1023) / 1024;
    int lo = tid * chunk;
    int hi = lo + chunk;
    if (lo > n) lo = n;
    if (hi > n) hi = n;
    int s = 0;
    for (int i = lo; i < hi; ++i) s += deg[i];
    part[tid] = s;
    __syncthreads();
    for (int off = 1; off < 1024; off <<= 1) {
        int v = (tid >= off) ? part[tid - off] : 0;
        __syncthreads();
        part[tid] += v;
        __syncthreads();
    }
    int run = (tid == 0) ? 0 : part[tid - 1];
    for (int i = lo; i < hi; ++i) {
        rowptr[i] = run;
        cursor[i] = run;
        run += deg[i];
    }
    if (tid == 1023) rowptr[n] = run;
}

__global__ void edge_scatter_k(const int* __restrict__ ei, int E, int n,
                               int* __restrict__ cursor, int* __restrict__ srcs) {
    int i = blockIdx.x * blockDim.x + threadIdx.x;
    if (i >= E + n) return;
    int src, dst;
    if (i < E) { src = ei[i]; dst = ei[E + i]; }
    else       { src = i - E; dst = src; }
    int pos = atomicAdd(&cursor[dst], 1);
    srcs[pos] = src;
}

// ---------------- bf16 split conversions ----------------
__global__ void split_bf16_k(const float* __restrict__ in, u16* __restrict__ hi,
                             u16* __restrict__ lo, int n4) {
    int i = blockIdx.x * 256 + threadIdx.x;
    if (i >= n4) return;
    float4 v = reinterpret_cast<const float4*>(in)[i];
    u16 hx = bf16rn(v.x), hy = bf16rn(v.y), hz = bf16rn(v.z), hw = bf16rn(v.w);
    ushort4 H = make_ushort4(hx, hy, hz, hw);
    ushort4 L = make_ushort4(bf16rn(v.x - bf16f(hx)), bf16rn(v.y - bf16f(hy)),
                             bf16rn(v.z - bf16f(hz)), bf16rn(v.w - bf16f(hw)));
    reinterpret_cast<ushort4*>(hi)[i] = H;
    reinterpret_cast<ushort4*>(lo)[i] = L;
}

// W[K][Nn] row-major -> transposed split Wt[Nn][K] (hi, lo)
__global__ void splitT_bf16_k(const float* __restrict__ W, u16* __restrict__ thi,
                              u16* __restrict__ tlo, int K, int Nn) {
    int idx = blockIdx.x * 256 + threadIdx.x;
    if (idx >= K * Nn) return;
    int k = idx / Nn, nn = idx - k * Nn;
    float v = W[idx];
    u16 h = bf16rn(v);
    u16 l = bf16rn(v - bf16f(h));
    thi[(size_t)nn * K + k] = h;
    tlo[(size_t)nn * K + k] = l;
}

// ---------------- split-bf16 MFMA GEMM, LDS-staged A, fused attn scores ----
// C[M,Nn] = (Ahi+Alo)[M,K] @ (Bhi+Blo)[K,Nn]; heads are 64-col groups of C.
// Epilogue also emits esrc/edst [M][Nn/64]: per-row dot with a_src/a_dst.
template <int NF>
__global__ __launch_bounds__(256) void gemm_lds_k(
        const u16* __restrict__ Ahi, const u16* __restrict__ Alo,
        const u16* __restrict__ Bthi, const u16* __restrict__ Btlo,
        float* __restrict__ C,
        const float* __restrict__ a_src, const float* __restrict__ a_dst,
        float* __restrict__ esrc, float* __restrict__ edst,
        int M, int Nn, int K) {
    __shared__ u16 Ah[2][4][64 * 8];   // [buf][kg][row*8]
    __shared__ u16 Al[2][4][64 * 8];
    const int mb = (M + 63) >> 6;
    const int mi = blockIdx.x % mb;
    const int ni = blockIdx.x / mb;
    const int m0 = mi * 64;
    const int n0 = ni * (NF * 64);
    const int tid = threadIdx.x;
    const int wv = tid >> 6;
    const int lane = tid & 63;
    const int rr = lane & 15;
    const int kg = lane >> 4;

    int srow = m0 + lane; if (srow > M - 1) srow = M - 1;
    const u16* sh = Ahi + (size_t)srow * K + wv * 8;
    const u16* sl = Alo + (size_t)srow * K + wv * 8;

    const u16* pbh[NF];
    const u16* pbl[NF];
#pragma unroll
    for (int nf = 0; nf < NF; ++nf) {
        int col = n0 + (wv * NF + nf) * 16 + rr;
        pbh[nf] = Bthi + (size_t)col * K + kg * 8;
        pbl[nf] = Btlo + (size_t)col * K + kg * 8;
    }

    f32x4 acc[4][NF];
#pragma unroll
    for (int mf = 0; mf < 4; ++mf)
#pragma unroll
        for (int nf = 0; nf < NF; ++nf) acc[mf][nf] = (f32x4){0.f, 0.f, 0.f, 0.f};

    bf16x8 bhc[NF], blc[NF], bhn[NF], bln[NF];
#pragma unroll
    for (int nf = 0; nf < NF; ++nf) {
        bhc[nf] = *reinterpret_cast<const bf16x8*>(pbh[nf]);
        blc[nf] = *reinterpret_cast<const bf16x8*>(pbl[nf]);
    }
    gload16(sh, &Ah[0][wv][0]);
    gload16(sl, &Al[0][wv][0]);
    __syncthreads();

    const int NT = K >> 5;
    for (int t = 0; t < NT; ++t) {
        const int cur = t & 1;
        if (t + 1 < NT) {
            const int kc = (t + 1) << 5;
#pragma unroll
            for (int nf = 0; nf < NF; ++nf) {
                bhn[nf] = *reinterpret_cast<const bf16x8*>(pbh[nf] + kc);
                bln[nf] = *reinterpret_cast<const bf16x8*>(pbl[nf] + kc);
            }
            gload16(sh + kc, &Ah[cur ^ 1][wv][0]);
            gload16(sl + kc, &Al[cur ^ 1][wv][0]);
        }
        bf16x8 ah[4], al[4];
#pragma unroll
        for (int mf = 0; mf < 4; ++mf) {
            ah[mf] = *reinterpret_cast<const bf16x8*>(&Ah[cur][kg][(mf * 16 + rr) * 8]);
            al[mf] = *reinterpret_cast<const bf16x8*>(&Al[cur][kg][(mf * 16 + rr) * 8]);
        }
#pragma unroll
        for (int mf = 0; mf < 4; ++mf)
#pragma unroll
            for (int nf = 0; nf < NF; ++nf) {
                acc[mf][nf] = __builtin_amdgcn_mfma_f32_16x16x32_bf16(ah[mf], bhc[nf], acc[mf][nf], 0, 0, 0);
                acc[mf][nf] = __builtin_amdgcn_mfma_f32_16x16x32_bf16(ah[mf], blc[nf], acc[mf][nf], 0, 0, 0);
                acc[mf][nf] = __builtin_amdgcn_mfma_f32_16x16x32_bf16(al[mf], bhc[nf], acc[mf][nf], 0, 0, 0);
            }
#pragma unroll
        for (int nf = 0; nf < NF; ++nf) { bhc[nf] = bhn[nf]; blc[nf] = bln[nf]; }
        __syncthreads();
    }

    // ---- C store ----
#pragma unroll
    for (int mf = 0; mf < 4; ++mf)
#pragma unroll
        for (int nf = 0; nf < NF; ++nf)
#pragma unroll
            for (int rg = 0; rg < 4; ++rg) {
                int row = m0 + mf * 16 + kg * 4 + rg;
                if (row < M)
                    C[(size_t)row * Nn + n0 + (wv * NF + nf) * 16 + rr] = acc[mf][nf][rg];
            }

    // ---- fused attention scores: per-row dot with a_src / a_dst ----
    float asv[NF], adv[NF];
#pragma unroll
    for (int nf = 0; nf < NF; ++nf) {
        int col = n0 + (wv * NF + nf) * 16 + rr;
        asv[nf] = a_src[col];
        adv[nf] = a_dst[col];
    }
    float ps[4][4], pd[4][4];   // [mf][rg]
#pragma unroll
    for (int mf = 0; mf < 4; ++mf)
#pragma unroll
        for (int rg = 0; rg < 4; ++rg) {
            float s = 0.f, dvv = 0.f;
#pragma unroll
            for (int nf = 0; nf < NF; ++nf) {
                s = fmaf(acc[mf][nf][rg], asv[nf], s);
                dvv = fmaf(acc[mf][nf][rg], adv[nf], dvv);
            }
#pragma unroll
            for (int off = 1; off < 16; off <<= 1) {
                s += __shfl_xor(s, off);
                dvv += __shfl_xor(dvv, off);
            }
            ps[mf][rg] = s;
            pd[mf][rg] = dvv;
        }
    // cross-wave combine via LDS (reuse Ah; all reads of it completed)
    float* sm_src = (float*)&Ah[0][0][0];     // [4 waves][64 rows]
    float* sm_dst = sm_src + 256;
    if (rr == 0) {
#pragma unroll
        for (int mf = 0; mf < 4; ++mf)
#pragma unroll
            for (int rg = 0; rg < 4; ++rg) {
                int rl = mf * 16 + kg * 4 + rg;
                sm_src[wv * 64 + rl] = ps[mf][rg];
                sm_dst[wv * 64 + rl] = pd[mf][rg];
            }
    }
    __syncthreads();
    if (tid < 64) {
        int row = m0 + tid;
        if (row < M) {
            const int HTOT = Nn >> 6;
            constexpr int WPH = 4 / NF;        // waves per head
#pragma unroll
            for (int hl = 0; hl < NF; ++hl) {
                float es = 0.f, edv = 0.f;
#pragma unroll
                for (int w = 0; w < WPH; ++w) {
                    es += sm_src[(hl * WPH + w) * 64 + tid];
                    edv += sm_dst[(hl * WPH + w) * 64 + tid];
                }
                int hg = ni * NF + hl;
                esrc[(size_t)row * HTOT + hg] = es;
                edst[(size_t)row * HTOT + hg] = edv;
            }
        }
    }
}

// ---------------- GAT aggregation, HEADS=4: one wave per dst node ----------
// Batched weights (1 vector exp per 32 edges) + 8-deep float4 row prefetch.
__global__ __launch_bounds__(256) void gat_aggregate4_k(
        const float* __restrict__ hin, const float* __restrict__ esrc,
        const float* __restrict__ edst, const int* __restrict__ rowptr,
        const int* __restrict__ srcs, const float* __restrict__ bias,
        u16* __restrict__ ghi, u16* __restrict__ glo, int n) {
    int d = blockIdx.x * 4 + (threadIdx.x >> 6);
    int lane = threadIdx.x & 63;
    if (d >= n) return;
    const int hh = lane >> 4;
    const int jj = lane & 15;
    float ed = edst[d * 4 + hh];
    int lo = rowptr[d], hi = rowptr[d + 1];
    float4 acc = make_float4(0.f, 0.f, 0.f, 0.f);
    float den = 0.f;
    for (int base = lo; base < hi; base += 32) {
        int cnt = min(32, hi - base);
        // --- batched weights for up to 32 edges ---
        int i0 = base + jj, i1 = base + 16 + jj;
        int s0 = srcs[(i0 < hi) ? i0 : lo];
        int s1 = srcs[(i1 < hi) ? i1 : lo];
        float e0 = esrc[s0 * 4 + hh] + ed;
        e0 = (e0 >= 0.f) ? e0 : 0.2f * e0;
        float w0 = (jj < cnt) ? __expf(e0) : 0.f;
        float e1 = esrc[s1 * 4 + hh] + ed;
        e1 = (e1 >= 0.f) ? e1 : 0.2f * e1;
        float w1 = (jj + 16 < cnt) ? __expf(e1) : 0.f;
        float ws = w0 + w1;
#pragma unroll
        for (int off = 1; off < 16; off <<= 1) ws += __shfl_xor(ws, off);
        den += ws;
        // --- multiply, 8-deep prefetch (named regs, clamped addresses) ---
        auto loadrow = [&](int j) -> float4 {
            j = (j < cnt) ? j : (cnt - 1);
            int sp = __shfl((j < 16) ? s0 : s1, j & 15);
            return *reinterpret_cast<const float4*>(&hin[(size_t)sp * 256 + lane * 4]);
        };
        auto wsel = [&](int j) -> float {
            return __shfl((j < 16) ? w0 : w1, (lane & 48) | (j & 15));
        };
        float4 p0 = loadrow(0), p1 = loadrow(1), p2 = loadrow(2), p3 = loadrow(3);
        float4 p4 = loadrow(4), p5 = loadrow(5), p6 = loadrow(6), p7 = loadrow(7);
        for (int j = 0; j < cnt; j += 8) {
            float4 q0 = p0, q1 = p1, q2 = p2, q3 = p3;
            float4 q4 = p4, q5 = p5, q6 = p6, q7 = p7;
            p0 = loadrow(j + 8);  p1 = loadrow(j + 9);
            p2 = loadrow(j + 10); p3 = loadrow(j + 11);
            p4 = loadrow(j + 12); p5 = loadrow(j + 13);
            p6 = loadrow(j + 14); p7 = loadrow(j + 15);
            float wA = wsel(j),     wB = wsel(j + 1), wC = wsel(j + 2), wD = wsel(j + 3);
            float wE = wsel(j + 4), wF = wsel(j + 5), wG = wsel(j + 6), wH = wsel(j + 7);
            acc.x = fmaf(wA, q0.x, acc.x); acc.y = fmaf(wA, q0.y, acc.y);
            acc.z = fmaf(wA, q0.z, acc.z); acc.w = fmaf(wA, q0.w, acc.w);
            acc.x = fmaf(wB, q1.x, acc.x); acc.y = fmaf(wB, q1.y, acc.y);
            acc.z = fmaf(wB, q1.z, acc.z); acc.w = fmaf(wB, q1.w, acc.w);
            acc.x = fmaf(wC, q2.x, acc.x); acc.y = fmaf(wC, q2.y, acc.y);
            acc.z = fmaf(wC, q2.z, acc.z); acc.w = fmaf(wC, q2.w, acc.w);
            acc.x = fmaf(wD, q3.x, acc.x); acc.y = fmaf(wD, q3.y, acc.y);
            acc.z = fmaf(wD, q3.z, acc.z); acc.w = fmaf(wD, q3.w, acc.w);
            acc.x = fmaf(wE, q4.x, acc.x); acc.y = fmaf(wE, q4.y, acc.y);
            acc.z = fmaf(wE, q4.z, acc.z); acc.w = fmaf(wE, q4.w, acc.w);
            acc.x = fmaf(wF, q5.x, acc.x); acc.y = fmaf(wF, q5.y, acc.y);
            acc.z = fmaf(wF, q5.z, acc.z); acc.w = fmaf(wF, q5.w, acc.w);
            acc.x = fmaf(wG, q6.x, acc.x); acc.y = fmaf(wG, q6.y, acc.y);
            acc.z = fmaf(wG, q6.z, acc.z); acc.w = fmaf(wG, q6.w, acc.w);
            acc.x = fmaf(wH, q7.x, acc.x); acc.y = fmaf(wH, q7.y, acc.y);
            acc.z = fmaf(wH, q7.z, acc.z); acc.w = fmaf(wH, q7.w, acc.w);
        }
    }
    float inv = 1.f / den;
    float4 bv = *reinterpret_cast<const float4*>(&bias[lane * 4]);
    float4 o;
    o.x = acc.x * inv + bv.x;
    o.y = acc.y * inv + bv.y;
    o.z = acc.z * inv + bv.z;
    o.w = acc.w * inv + bv.w;
    o.x = (o.x > 0.f) ? o.x : expm1f(o.x);       // ELU
    o.y = (o.y > 0.f) ? o.y : expm1f(o.y);
    o.z = (o.z > 0.f) ? o.z : expm1f(o.z);
    o.w = (o.w > 0.f) ? o.w : expm1f(o.w);
    u16 hx = bf16rn(o.x), hy = bf16rn(o.y), hz = bf16rn(o.z), hw = bf16rn(o.w);
    ushort4 H = make_ushort4(hx, hy, hz, hw);
    ushort4 L = make_ushort4(bf16rn(o.x - bf16f(hx)), bf16rn(o.y - bf16f(hy)),
                             bf16rn(o.z - bf16f(hz)), bf16rn(o.w - bf16f(hw)));
    *reinterpret_cast<ushort4*>(&ghi[(size_t)d * 256 + lane * 4]) = H;
    *reinterpret_cast<ushort4*>(&glo[(size_t)d * 256 + lane * 4]) = L;
}

// ---------------- layer-3 aggregate (1 head) fused with node attn gate ------
__global__ __launch_bounds__(256) void gat_aggregate1_attn_k(
        const float* __restrict__ hin, const float* __restrict__ esrc,
        const float* __restrict__ edst, const int* __restrict__ rowptr,
        const int* __restrict__ srcs, const float* __restrict__ bias,
        const float* __restrict__ wp, const float* __restrict__ bp,
        float* __restrict__ gout, float* __restrict__ attn, int n) {
    int d = blockIdx.x * 4 + (threadIdx.x >> 6);
    int lane = threadIdx.x & 63;
    if (d >= n) return;
    float ed = edst[d];
    int lo = rowptr[d], hi = rowptr[d + 1];
    float den = 0.f, acc = 0.f;
    for (int base = lo; base < hi; base += 64) {
        int cnt = min(64, hi - base);
        int idx = base + lane;
        int s = srcs[(idx < hi) ? idx : lo];
        float e = esrc[s] + ed;
        e = (e >= 0.f) ? e : 0.2f * e;
        float w = (lane < cnt) ? __expf(e) : 0.f;
        float ws = w;
#pragma unroll
        for (int off = 1; off < 64; off <<= 1) ws += __shfl_xor(ws, off);
        den += ws;
        auto loadrow = [&](int j) -> float {
            j = (j < cnt) ? j : (cnt - 1);
            int sp = __shfl(s, j);
            return hin[(size_t)sp * 64 + lane];
        };
        float p0 = loadrow(0), p1 = loadrow(1), p2 = loadrow(2), p3 = loadrow(3);
        float p4 = loadrow(4), p5 = loadrow(5), p6 = loadrow(6), p7 = loadrow(7);
        for (int j = 0; j < cnt; j += 8) {
            float q0 = p0, q1 = p1, q2 = p2, q3 = p3;
            float q4 = p4, q5 = p5, q6 = p6, q7 = p7;
            p0 = loadrow(j + 8);  p1 = loadrow(j + 9);
            p2 = loadrow(j + 10); p3 = loadrow(j + 11);
            p4 = loadrow(j + 12); p5 = loadrow(j + 13);
            p6 = loadrow(j + 14); p7 = loadrow(j + 15);
            acc = fmaf(__shfl(w, j), q0, acc);
            acc = fmaf(__shfl(w, j + 1), q1, acc);
            acc = fmaf(__shfl(w, j + 2), q2, acc);
            acc = fmaf(__shfl(w, j + 3), q3, acc);
            acc = fmaf(__shfl(w, j + 4), q4, acc);
            acc = fmaf(__shfl(w, j + 5), q5, acc);
            acc = fmaf(__shfl(w, j + 6), q6, acc);
            acc = fmaf(__shfl(w, j + 7), q7, acc);
        }
    }
    float o = acc / den + bias[lane];
    o = (o > 0.f) ? o : expm1f(o);               // ELU
    gout[(size_t)d * 64 + lane] = o;
    float v = o * wp[lane];
#pragma unroll
    for (int off = 32; off; off >>= 1) v += __shfl_xor(v, off);
    if (lane == 0) attn[d] = 1.f / (1.f + __expf(-(v + bp[0])));
}

// ---------------- parallel segmented pooling (batch is sorted) --------------
__global__ void pool_partial_k(const float* __restrict__ g3, const float* __restrict__ attn,
                               const int* __restrict__ batch, int n, float* __restrict__ sums) {
    int wid = blockIdx.x * (blockDim.x >> 6) + (threadIdx.x >> 6);
    int lane = threadIdx.x & 63;
    int nwaves = gridDim.x * (blockDim.x >> 6);
    int per = (n + nwaves - 1) / nwaves;
    int i0 = wid * per;
    int i1 = i0 + per;
    if (i1 > n) i1 = n;
    if (i0 >= i1) return;
    int cur = batch[i0];
    float acc = 0.f;
    for (int i = i0; i < i1; ++i) {
        int b = batch[i];
        if (b != cur) {
            atomicAdd(&sums[cur * 64 + lane], acc);
            acc = 0.f;
            cur = b;
        }
        acc += g3[(size_t)i * 64 + lane] * attn[i];
    }
    atomicAdd(&sums[cur * 64 + lane], acc);
}

// ---------------- final regressor: one block, wave per graph ----------------
__global__ void regress_k(const float* __restrict__ sums, const int* __restrict__ batch, int n,
                          const float* __restrict__ wr, const float* __restrict__ br,
                          float* __restrict__ out, int B) {
    int b = threadIdx.x >> 6;
    int lane = threadIdx.x & 63;
    if (b >= B) return;
    int lo = 0, hi = n;
    while (lo < hi) { int mid = (lo + hi) >> 1; if (batch[mid] < b) lo = mid + 1; else hi = mid; }
    int seg_lo = lo;
    lo = 0; hi = n;
    while (lo < hi) { int mid = (lo + hi) >> 1; if (batch[mid] < b + 1) lo = mid + 1; else hi = mid; }
    float cnt = (float)(lo - seg_lo);
    if (cnt < 1.f) cnt = 1.f;
    float v = (sums[b * 64 + lane] / cnt) * wr[lane];
#pragma unroll
    for (int off = 32; off; off >>= 1) v += __shfl_xor(v, off);
    if (lane == 0) out[b] = v + br[0];
}

// ---------------------------------------------------------------------------
extern "C" void kernel_launch(void* const* d_in, const int* in_sizes, int n_in,
                              void* d_out, int out_size, void* d_ws, size_t ws_size,
                              hipStream_t stream) {
    const float* x   = (const float*)d_in[0];
    const int*   ei  = (const int*)d_in[1];
    const int*   bat = (const int*)d_in[2];
    const float* W1  = (const float*)d_in[3];
    const float* as1 = (const float*)d_in[4];
    const float* ad1 = (const float*)d_in[5];
    const float* b1  = (const float*)d_in[6];
    const float* W2  = (const float*)d_in[7];
    const float* as2 = (const float*)d_in[8];
    const float* ad2 = (const float*)d_in[9];
    const float* b2  = (const float*)d_in[10];
    const float* W3  = (const float*)d_in[11];
    const float* as3 = (const float*)d_in[12];
    const float* ad3 = (const float*)d_in[13];
    const float* b3  = (const float*)d_in[14];
    const float* wp  = (const float*)d_in[15];
    const float* bp  = (const float*)d_in[16];
    const float* wr  = (const float*)d_in[17];
    const float* br  = (const float*)d_in[18];
    float* out = (float*)d_out;

    const int N    = in_sizes[2];          // 20000
    const int E    = in_sizes[1] / 2;      // 320000
    const int DIN  = in_sizes[0] / N;      // 128
    const int Etot = E + N;
    const int Bc   = out_size;             // 16

    char* ws = (char*)d_ws;
    size_t off = 0;
    auto alloc = [&](size_t bytes) {
        void* p = ws + off;
        off = (off + bytes + 255) & ~(size_t)255;
        return p;
    };
    int*   deg    = (int*)alloc((size_t)N * 4);
    int*   rowptr = (int*)alloc((size_t)(N + 1) * 4);
    int*   cursor = (int*)alloc((size_t)N * 4);
    int*   srcs   = (int*)alloc((size_t)Etot * 4);
    float* bufA   = (float*)alloc((size_t)N * 256 * 4);     // GEMM out h (f32)
    u16*   Ahi    = (u16*)alloc((size_t)N * 256 * 2);       // x/g split hi
    u16*   Alo    = (u16*)alloc((size_t)N * 256 * 2);       // x/g split lo
    float* h3     = (float*)alloc((size_t)N * 64 * 4);
    float* g3     = (float*)alloc((size_t)N * 64 * 4);
    float* esrc   = (float*)alloc((size_t)N * 4 * 4);
    float* edst   = (float*)alloc((size_t)N * 4 * 4);
    float* attn   = (float*)alloc((size_t)N * 4);
    float* sums   = (float*)alloc((size_t)Bc * 64 * 4);
    u16*   w1hi   = (u16*)alloc((size_t)256 * DIN * 2);
    u16*   w1lo   = (u16*)alloc((size_t)256 * DIN * 2);
    u16*   w2hi   = (u16*)alloc((size_t)256 * 256 * 2);
    u16*   w2lo   = (u16*)alloc((size_t)256 * 256 * 2);
    u16*   w3hi   = (u16*)alloc((size_t)64 * 256 * 2);
    u16*   w3lo   = (u16*)alloc((size_t)64 * 256 * 2);
    (void)ws_size;

    // CSR build (shared by all layers)
    hipMemsetAsync(deg, 0, (size_t)N * 4, stream);
    int eb = (Etot + 255) / 256;
    edge_hist_k<<<eb, 256, 0, stream>>>(ei, E, N, deg);
    scan_excl_k<<<1, 1024, 0, stream>>>(deg, rowptr, cursor, N);
    edge_scatter_k<<<eb, 256, 0, stream>>>(ei, E, N, cursor, srcs);

    // weight splits (transposed) + x split
    splitT_bf16_k<<<(DIN * 256 + 255) / 256, 256, 0, stream>>>(W1, w1hi, w1lo, DIN, 256);
    splitT_bf16_k<<<(256 * 256 + 255) / 256, 256, 0, stream>>>(W2, w2hi, w2lo, 256, 256);
    splitT_bf16_k<<<(256 * 64 + 255) / 256, 256, 0, stream>>>(W3, w3hi, w3lo, 256, 64);
    split_bf16_k<<<(N * DIN / 4 + 255) / 256, 256, 0, stream>>>(x, Ahi, Alo, N * DIN / 4);

    const int mb = (N + 63) / 64;          // 313
    int nb4 = (N + 3) / 4;

    // Layer 1: DIN -> (4,64) concat      (BN=128 -> 2 n-tiles)
    gemm_lds_k<2><<<mb * 2, 256, 0, stream>>>(Ahi, Alo, w1hi, w1lo, bufA, as1, ad1, esrc, edst, N, 256, DIN);
    gat_aggregate4_k<<<nb4, 256, 0, stream>>>(bufA, esrc, edst, rowptr, srcs, b1, Ahi, Alo, N);

    // Layer 2: 256 -> (4,64) concat
    gemm_lds_k<2><<<mb * 2, 256, 0, stream>>>(Ahi, Alo, w2hi, w2lo, bufA, as2, ad2, esrc, edst, N, 256, 256);
    gat_aggregate4_k<<<nb4, 256, 0, stream>>>(bufA, esrc, edst, rowptr, srcs, b2, Ahi, Alo, N);

    // Layer 3: 256 -> (1,64) mean + fused node-attention gate   (BN=64)
    gemm_lds_k<1><<<mb, 256, 0, stream>>>(Ahi, Alo, w3hi, w3lo, h3, as3, ad3, esrc, edst, N, 64, 256);
    gat_aggregate1_attn_k<<<nb4, 256, 0, stream>>>(h3, esrc, edst, rowptr, srcs, b3, wp, bp, g3, attn, N);

    // Attention pool + regressor (parallel)
    hipMemsetAsync(sums, 0, (size_t)Bc * 64 * 4, stream);
    pool_partial_k<<<256, 256, 0, stream>>>(g3, attn, bat, N, sums);
    regress_k<<<1, 1024, 0, stream>>>(sums, bat, N, wr, br, out, Bc);
}